// Round 1
// baseline (2831.325 us; speedup 1.0000x reference)
//
#include <hip/hip_runtime.h>
#include <math.h>

#define TT 16
#define NN 10000
#define EE 320000
#define FF 128
#define HH 256
#define LL 64
#define HLL 256

__device__ __forceinline__ float sigm(float x) { return 1.0f / (1.0f + expf(-x)); }

// ---------------- preprocessing ----------------

__global__ void pre_deg(const int* __restrict__ src, const int* __restrict__ dst,
                        const float* __restrict__ ea, float* __restrict__ deg_enc,
                        int* __restrict__ cnt) {
    int e = blockIdx.x * 256 + threadIdx.x;
    if (e >= EE) return;
    int d = dst[e];
    atomicAdd(&deg_enc[d], ea[e]);
    atomicAdd(&cnt[d], 1);
}

__global__ void pre_dis(const float* __restrict__ deg_enc, const int* __restrict__ cnt,
                        float* __restrict__ dis_enc, float* __restrict__ dis_dec,
                        float* __restrict__ sn_enc, float* __restrict__ sn_dec) {
    int n = blockIdx.x * 256 + threadIdx.x;
    if (n >= NN) return;
    float de = deg_enc[n] + 1.0f;             // + self-loop weight 1
    float dd = (float)cnt[n] + 1.0f;
    dis_enc[n] = rsqrtf(de);
    dis_dec[n] = rsqrtf(dd);
    sn_enc[n] = 1.0f / de;                    // dis^2 * selfweight(=1)
    sn_dec[n] = 1.0f / dd;
}

// single-block inclusive scan -> row_ptr (N=10000, 1024 threads, 10 chunks)
__global__ void scan_rowptr(const int* __restrict__ cnt, int* __restrict__ row_ptr) {
    __shared__ int sb[1024];
    int tx = threadIdx.x;
    int run = 0;
    if (tx == 0) row_ptr[0] = 0;
    for (int base = 0; base < NN; base += 1024) {
        int i = base + tx;
        int v = (i < NN) ? cnt[i] : 0;
        sb[tx] = v;
        __syncthreads();
        for (int off = 1; off < 1024; off <<= 1) {
            int t = (tx >= off) ? sb[tx - off] : 0;
            __syncthreads();
            sb[tx] += t;
            __syncthreads();
        }
        if (i < NN) row_ptr[i + 1] = run + sb[tx];
        run += sb[1023];
        __syncthreads();
    }
}

__global__ void pre_build(const int* __restrict__ src, const int* __restrict__ dst,
                          const float* __restrict__ ea, const int* __restrict__ row_ptr,
                          int* __restrict__ cursor, const float* __restrict__ dis_enc,
                          const float* __restrict__ dis_dec, int* __restrict__ src_s,
                          float* __restrict__ w_enc, float* __restrict__ w_dec) {
    int e = blockIdx.x * 256 + threadIdx.x;
    if (e >= EE) return;
    int s = src[e], d = dst[e];
    int pos = row_ptr[d] + atomicAdd(&cursor[d], 1);
    src_s[pos] = s;
    w_enc[pos] = dis_enc[s] * ea[e] * dis_enc[d];
    w_dec[pos] = dis_dec[s] * dis_dec[d];
}

// ---------------- sparse A @ X (CSR, no atomics) ----------------
// out[n,c] = selfw[n]*in[n,c] + sum_j w[j]*in[src[j],c]  (+bias, relu)
template <int C_, bool BIAS, bool RELU>
__global__ __launch_bounds__(256) void spmm_csr(
    const float* __restrict__ in, float* __restrict__ out,
    const int* __restrict__ rp, const int* __restrict__ srcs,
    const float* __restrict__ w, const float* __restrict__ selfw,
    const float* __restrict__ bias, long sIn, long sOut) {
    in += (long)blockIdx.z * sIn;
    out += (long)blockIdx.z * sOut;
    constexpr int NPB = 256 / C_;
    int node = blockIdx.x * NPB + threadIdx.x / C_;
    int c = threadIdx.x % C_;
    if (node >= NN) return;
    float acc = selfw[node] * in[(long)node * C_ + c];
    int j = rp[node], s1 = rp[node + 1];
    for (; j + 1 < s1; j += 2) {
        int sA = srcs[j], sB = srcs[j + 1];
        float wA = w[j], wB = w[j + 1];
        acc += wA * in[(long)sA * C_ + c];
        acc += wB * in[(long)sB * C_ + c];
    }
    if (j < s1) acc += w[j] * in[(long)srcs[j] * C_ + c];
    if (BIAS) acc += bias[c];
    if (RELU) acc = fmaxf(acc, 0.0f);
    out[(long)node * C_ + c] = acc;
}

// ---------------- fp32 tiled GEMM: C = act(A[M,K] @ B[K,Nc] + bias) ----------------
template <bool BIAS, bool RELU>
__global__ __launch_bounds__(256) void gemm_f32(
    const float* __restrict__ A, const float* __restrict__ B,
    const float* __restrict__ bias, float* __restrict__ Cm,
    int M, int Nc, int K, long sA, long sC) {
    A += (long)blockIdx.z * sA;
    Cm += (long)blockIdx.z * sC;
    __shared__ float As[16][68];
    __shared__ float Bs[16][68];
    int tid = threadIdx.x;
    int bm = blockIdx.y * 64, bn = blockIdx.x * 64;
    int tx = tid % 16, ty = tid / 16;
    int am = tid / 4, ak = (tid % 4) * 4;
    int bk = tid / 16, bn4 = (tid % 16) * 4;
    float acc[4][4] = {};
    for (int k0 = 0; k0 < K; k0 += 16) {
        float4 av = make_float4(0.f, 0.f, 0.f, 0.f);
        if (bm + am < M) av = *(const float4*)&A[(long)(bm + am) * K + k0 + ak];
        As[ak + 0][am] = av.x;
        As[ak + 1][am] = av.y;
        As[ak + 2][am] = av.z;
        As[ak + 3][am] = av.w;
        *(float4*)&Bs[bk][bn4] = *(const float4*)&B[(long)(k0 + bk) * Nc + bn + bn4];
        __syncthreads();
#pragma unroll
        for (int kk = 0; kk < 16; ++kk) {
            float4 a = *(const float4*)&As[kk][ty * 4];
            float4 b = *(const float4*)&Bs[kk][tx * 4];
            acc[0][0] += a.x * b.x; acc[0][1] += a.x * b.y; acc[0][2] += a.x * b.z; acc[0][3] += a.x * b.w;
            acc[1][0] += a.y * b.x; acc[1][1] += a.y * b.y; acc[1][2] += a.y * b.z; acc[1][3] += a.y * b.w;
            acc[2][0] += a.z * b.x; acc[2][1] += a.z * b.y; acc[2][2] += a.z * b.z; acc[2][3] += a.z * b.w;
            acc[3][0] += a.w * b.x; acc[3][1] += a.w * b.y; acc[3][2] += a.w * b.z; acc[3][3] += a.w * b.w;
        }
        __syncthreads();
    }
#pragma unroll
    for (int i = 0; i < 4; ++i) {
        int r = bm + ty * 4 + i;
        if (r >= M) continue;
#pragma unroll
        for (int jj = 0; jj < 4; ++jj) {
            int col = bn + tx * 4 + jj;
            float v = acc[i][jj];
            if (BIAS) v += bias[col];
            if (RELU) v = fmaxf(v, 0.0f);
            Cm[(long)r * Nc + col] = v;
        }
    }
}

// ---------------- mean pool over nodes (per channel) ----------------
__global__ void col_mean(const float* __restrict__ in, float* __restrict__ pooled, long sIn) {
    in += (long)blockIdx.z * sIn;
    float* pt = pooled + (long)blockIdx.z * HH;
    int c = threadIdx.x;
    int n0 = blockIdx.x * 64;
    int n1 = min(n0 + 64, NN);
    float acc = 0.f;
    for (int n = n0; n < n1; ++n) acc += in[(long)n * HH + c];
    atomicAdd(&pt[c], acc * (1.0f / (float)NN));
}

// z[t] = pooled[t] @ Wfce + bfce
__global__ void enc_head(const float* __restrict__ pooled, const float* __restrict__ Wfce,
                         const float* __restrict__ bfce, float* __restrict__ z) {
    int t = blockIdx.x, j = threadIdx.x;  // 64 threads
    __shared__ float p[HH];
    for (int i = j; i < HH; i += 64) p[i] = pooled[t * HH + i];
    __syncthreads();
    float acc = bfce[j];
    for (int h = 0; h < HH; ++h) acc += p[h] * Wfce[h * LL + j];
    z[t * LL + j] = acc;
}

// G[t][j] = b1[j]+b2[j] + sum_k in[t,k]*Wih[k,j]
template <int IN>
__global__ void lstm_pre(const float* __restrict__ in, const float* __restrict__ Wih,
                         const float* __restrict__ b1, const float* __restrict__ b2,
                         float* __restrict__ G) {
    int t = blockIdx.y;
    int j = blockIdx.x * 256 + threadIdx.x;
    __shared__ float xs_[IN];
    for (int i = threadIdx.x; i < IN; i += 256) xs_[i] = in[t * IN + i];
    __syncthreads();
    float acc = b1[j] + b2[j];
    for (int k = 0; k < IN; ++k) acc += xs_[k] * Wih[k * 1024 + j];
    G[t * 1024 + j] = acc;
}

// one LSTM step: grid 4 blocks x 256 threads, block b owns units [b*64, b*64+64)
__global__ void lstm_step(const float* __restrict__ h_in, float* __restrict__ h_out,
                          float* __restrict__ c, const float* __restrict__ Gt,
                          const float* __restrict__ Whh, float* __restrict__ seq_out) {
    __shared__ float hs[HLL];
    __shared__ float gb[256];
    int tx = threadIdx.x;
    hs[tx] = h_in[tx];
    __syncthreads();
    int gate = tx >> 6, l = tx & 63;
    int j = gate * HLL + blockIdx.x * 64 + l;
    float acc = Gt[j];
    for (int k = 0; k < HLL; ++k) acc += hs[k] * Whh[k * 1024 + j];
    gb[tx] = acc;
    __syncthreads();
    if (tx < 64) {
        int u = blockIdx.x * 64 + tx;
        float ii = gb[tx], ff = gb[64 + tx], gg = gb[128 + tx], oo = gb[192 + tx];
        float cc = sigm(ff) * c[u] + sigm(ii) * tanhf(gg);
        c[u] = cc;
        float hh = sigm(oo) * tanhf(cc);
        h_out[u] = hh;
        if (seq_out) seq_out[u] = hh;
    }
}

__global__ void lstm_head(const float* __restrict__ h, const float* __restrict__ Whead,
                          const float* __restrict__ bhead, float* __restrict__ z) {
    int j = threadIdx.x;  // 64
    __shared__ float hs[HLL];
    for (int i = j; i < HLL; i += 64) hs[i] = h[i];
    __syncthreads();
    float acc = bhead[j];
    for (int k = 0; k < HLL; ++k) acc += hs[k] * Whead[k * LL + j];
    z[j] = acc;
}

// Xd[m..m+3] = relu(bfcd + sum_k z[k]*Wfcd[k, m..m+3]) ; 640000 outputs
__global__ void dec_fc(const float* __restrict__ z, const float* __restrict__ Wfcd,
                       const float* __restrict__ bfcd, float* __restrict__ Xd) {
    __shared__ float zs_[LL];
    if (threadIdx.x < LL) zs_[threadIdx.x] = z[threadIdx.x];
    __syncthreads();
    long m = ((long)blockIdx.x * 256 + threadIdx.x) * 4;
    if (m >= (long)NN * LL) return;
    float4 acc = *(const float4*)&bfcd[m];
#pragma unroll
    for (int k = 0; k < LL; ++k) {
        float4 w4 = *(const float4*)&Wfcd[(long)k * (NN * (long)LL) + m];
        float zk = zs_[k];
        acc.x += zk * w4.x; acc.y += zk * w4.y; acc.z += zk * w4.z; acc.w += zk * w4.w;
    }
    acc.x = fmaxf(acc.x, 0.f); acc.y = fmaxf(acc.y, 0.f);
    acc.z = fmaxf(acc.z, 0.f); acc.w = fmaxf(acc.w, 0.f);
    *(float4*)&Xd[m] = acc;
}

// ---------------- host ----------------

extern "C" void kernel_launch(void* const* d_in, const int* in_sizes, int n_in,
                              void* d_out, int out_size, void* d_ws, size_t ws_size,
                              hipStream_t stream) {
    const float* xs = (const float*)d_in[0];
    const float* edge_attr = (const float*)d_in[1];
    const float* We0 = (const float*)d_in[2];  const float* be0 = (const float*)d_in[3];
    const float* We1 = (const float*)d_in[4];  const float* be1 = (const float*)d_in[5];
    const float* Wfce = (const float*)d_in[6]; const float* bfce = (const float*)d_in[7];
    const float* Wih0 = (const float*)d_in[8]; const float* Whh0 = (const float*)d_in[9];
    const float* bih0 = (const float*)d_in[10]; const float* bhh0 = (const float*)d_in[11];
    const float* Wih1 = (const float*)d_in[12]; const float* Whh1 = (const float*)d_in[13];
    const float* bih1 = (const float*)d_in[14]; const float* bhh1 = (const float*)d_in[15];
    const float* Whead = (const float*)d_in[16]; const float* bhead = (const float*)d_in[17];
    const float* Wfcd = (const float*)d_in[18]; const float* bfcd = (const float*)d_in[19];
    const float* Wd0 = (const float*)d_in[20]; const float* bd0 = (const float*)d_in[21];
    const float* Wd1 = (const float*)d_in[22]; const float* bd1 = (const float*)d_in[23];
    const float* Wd2 = (const float*)d_in[24]; const float* bd2 = (const float*)d_in[25];
    const int* eidx = (const int*)d_in[26];
    const int* esrc = eidx;
    const int* edst = eidx + EE;
    float* out = (float*)d_out;
    float* W = (float*)d_ws;

    // ---- workspace layout (float offsets) ----
    const long O_DEG = 0;           // [10000] f32   (zeroed)
    const long O_CNT = 10000;       // [10000] i32   (zeroed)
    const long O_CUR = 20000;       // [10000] i32   (zeroed)
    const long O_POOL = 30000;      // [16*256]      (zeroed)
    const long O_LSTM = 34096;      // h0A,h0B,c0,h1A,h1B,c1 (6*256, zeroed)
    const long ZFLOATS = 36000;     // end of zero region
    const long O_DISE = 36000, O_DISD = 46000, O_SNE = 56000, O_SND = 66000;
    const long O_RP = 76000;        // [10001] i32 (pad to 10016)
    const long O_SRCS = 86016;      // [320000] i32
    const long O_WENC = 406016;     // [320000] f32
    const long O_WDEC = 726016;     // [320000] f32
    const long O_ZENC = 1046016;    // [16*64]
    const long O_G0 = 1047040;      // [16*1024]
    const long O_G1 = 1063424;      // [16*1024]
    const long O_H1S = 1079808;     // [16*256]
    const long O_ZDEC = 1083904;    // [64], pad
    const long O_B0 = 1084000;

    const long SB0 = (long)NN * FF;   // 1,280,000
    const long SB1 = (long)NN * HH;   // 2,560,000
    const long SB2 = (long)NN * HH;

    // batched (all 16 timesteps in flight) needs ~417 MB of ws
    const long needBatched = (O_B0 + 16 * (SB0 + SB1 + SB2) + (long)NN * LL) * 4;
    const bool batched = (long)ws_size >= needBatched;
    const long tb = batched ? 16 : 1;
    const long oB1 = O_B0 + tb * SB0;
    const long oB2 = oB1 + tb * SB1;
    const long oXD = oB2 + tb * SB2;

    float* deg = W + O_DEG;
    int* cnt = (int*)(W + O_CNT);
    int* cur = (int*)(W + O_CUR);
    float* pooled = W + O_POOL;
    float* h0A = W + O_LSTM, *h0B = h0A + 256, *c0 = h0B + 256;
    float* h1A = c0 + 256, *h1B = h1A + 256, *c1 = h1B + 256;
    float* dise = W + O_DISE, *disd = W + O_DISD, *sne = W + O_SNE, *snd = W + O_SND;
    int* rp = (int*)(W + O_RP);
    int* srcs = (int*)(W + O_SRCS);
    float* wenc = W + O_WENC, *wdec = W + O_WDEC;
    float* zenc = W + O_ZENC, *G0 = W + O_G0, *G1 = W + O_G1;
    float* H1seq = W + O_H1S, *zdec = W + O_ZDEC;
    float* B0 = W + O_B0, *B1 = W + oB1, *B2 = W + oB2, *XD = W + oXD;

    // ---- preprocessing ----
    hipMemsetAsync(d_ws, 0, ZFLOATS * 4, stream);
    pre_deg<<<(EE + 255) / 256, 256, 0, stream>>>(esrc, edst, edge_attr, deg, cnt);
    pre_dis<<<(NN + 255) / 256, 256, 0, stream>>>(deg, cnt, dise, disd, sne, snd);
    scan_rowptr<<<1, 1024, 0, stream>>>(cnt, rp);
    pre_build<<<(EE + 255) / 256, 256, 0, stream>>>(esrc, edst, edge_attr, rp, cur, dise, disd,
                                                    srcs, wenc, wdec);

    // ---- encoder: per t: AX = A@X_t; H1 = relu(AX@We0+be0); G = H1@We1;
    //                H2 = relu(A@G+be1); pooled[t] = mean_n(H2) ----
    if (batched) {
        spmm_csr<128, false, false><<<dim3(NN / 2, 1, 16), 256, 0, stream>>>(
            xs, B0, rp, srcs, wenc, sne, nullptr, SB0, SB0);
        gemm_f32<true, true><<<dim3(4, 157, 16), 256, 0, stream>>>(
            B0, We0, be0, B1, NN, HH, FF, SB0, SB1);
        gemm_f32<false, false><<<dim3(4, 157, 16), 256, 0, stream>>>(
            B1, We1, nullptr, B2, NN, HH, HH, SB1, SB2);
        spmm_csr<256, true, true><<<dim3(NN, 1, 16), 256, 0, stream>>>(
            B2, B1, rp, srcs, wenc, sne, be1, SB2, SB1);
        col_mean<<<dim3(157, 1, 16), 256, 0, stream>>>(B1, pooled, SB1);
    } else {
        for (int t = 0; t < TT; ++t) {
            spmm_csr<128, false, false><<<dim3(NN / 2, 1, 1), 256, 0, stream>>>(
                xs + (long)t * SB0, B0, rp, srcs, wenc, sne, nullptr, 0, 0);
            gemm_f32<true, true><<<dim3(4, 157, 1), 256, 0, stream>>>(
                B0, We0, be0, B1, NN, HH, FF, 0, 0);
            gemm_f32<false, false><<<dim3(4, 157, 1), 256, 0, stream>>>(
                B1, We1, nullptr, B2, NN, HH, HH, 0, 0);
            spmm_csr<256, true, true><<<dim3(NN, 1, 1), 256, 0, stream>>>(
                B2, B1, rp, srcs, wenc, sne, be1, 0, 0);
            col_mean<<<dim3(157, 1, 1), 256, 0, stream>>>(B1, pooled + t * HH, 0);
        }
    }
    enc_head<<<16, 64, 0, stream>>>(pooled, Wfce, bfce, zenc);

    // ---- LSTM ----
    lstm_pre<64><<<dim3(4, 16), 256, 0, stream>>>(zenc, Wih0, bih0, bhh0, G0);
    {
        float* hi = h0A; float* ho = h0B;
        for (int t = 0; t < TT; ++t) {
            lstm_step<<<4, 256, 0, stream>>>(hi, ho, c0, G0 + t * 1024, Whh0, H1seq + t * HLL);
            float* tmp = hi; hi = ho; ho = tmp;
        }
    }
    lstm_pre<256><<<dim3(4, 16), 256, 0, stream>>>(H1seq, Wih1, bih1, bhh1, G1);
    float* hfinal;
    {
        float* hi = h1A; float* ho = h1B;
        for (int t = 0; t < TT; ++t) {
            lstm_step<<<4, 256, 0, stream>>>(hi, ho, c1, G1 + t * 1024, Whh1, nullptr);
            float* tmp = hi; hi = ho; ho = tmp;
        }
        hfinal = hi;
    }
    lstm_head<<<1, 64, 0, stream>>>(hfinal, Whead, bhead, zdec);

    // ---- decoder ----
    dec_fc<<<625, 256, 0, stream>>>(zdec, Wfcd, bfcd, XD);
    spmm_csr<64, false, false><<<dim3(NN / 4, 1, 1), 256, 0, stream>>>(
        XD, B0, rp, srcs, wdec, snd, nullptr, 0, 0);
    gemm_f32<true, true><<<dim3(4, 157, 1), 256, 0, stream>>>(
        B0, Wd0, bd0, B1, NN, HH, LL, 0, 0);
    gemm_f32<false, false><<<dim3(4, 157, 1), 256, 0, stream>>>(
        B1, Wd1, nullptr, B2, NN, HH, HH, 0, 0);
    spmm_csr<256, true, true><<<dim3(NN, 1, 1), 256, 0, stream>>>(
        B2, B1, rp, srcs, wdec, snd, bd1, 0, 0);
    gemm_f32<false, false><<<dim3(2, 157, 1), 256, 0, stream>>>(
        B1, Wd2, nullptr, B0, NN, FF, HH, 0, 0);
    spmm_csr<128, true, false><<<dim3(NN / 2, 1, 1), 256, 0, stream>>>(
        B0, out, rp, srcs, wdec, snd, bd2, 0, 0);
}

// Round 2
// 1431.562 us; speedup vs baseline: 1.9778x; 1.9778x over previous
//
#include <hip/hip_runtime.h>
#include <math.h>

#define TT 16
#define NN 10000
#define EE 320000
#define FF 128
#define HH 256
#define LL 64
#define HLL 256

typedef _Float16 h16;
typedef _Float16 half4 __attribute__((ext_vector_type(4)));
typedef _Float16 half8 __attribute__((ext_vector_type(8)));
typedef float floatx4 __attribute__((ext_vector_type(4)));

__device__ __forceinline__ float sigm(float x) { return 1.0f / (1.0f + expf(-x)); }

// ---------------- preprocessing ----------------

__global__ void pre_deg(const int* __restrict__ src, const int* __restrict__ dst,
                        const float* __restrict__ ea, float* __restrict__ deg_enc,
                        int* __restrict__ cnt) {
    int e = blockIdx.x * 256 + threadIdx.x;
    if (e >= EE) return;
    int d = dst[e];
    atomicAdd(&deg_enc[d], ea[e]);
    atomicAdd(&cnt[d], 1);
}

__global__ void pre_dis(const float* __restrict__ deg_enc, const int* __restrict__ cnt,
                        float* __restrict__ dis_enc, float* __restrict__ dis_dec,
                        float* __restrict__ sn_enc, float* __restrict__ sn_dec) {
    int n = blockIdx.x * 256 + threadIdx.x;
    if (n >= NN) return;
    float de = deg_enc[n] + 1.0f;
    float dd = (float)cnt[n] + 1.0f;
    dis_enc[n] = rsqrtf(de);
    dis_dec[n] = rsqrtf(dd);
    sn_enc[n] = 1.0f / de;
    sn_dec[n] = 1.0f / dd;
}

__global__ void scan_rowptr(const int* __restrict__ cnt, int* __restrict__ row_ptr) {
    __shared__ int sb[1024];
    int tx = threadIdx.x;
    int run = 0;
    if (tx == 0) row_ptr[0] = 0;
    for (int base = 0; base < NN; base += 1024) {
        int i = base + tx;
        int v = (i < NN) ? cnt[i] : 0;
        sb[tx] = v;
        __syncthreads();
        for (int off = 1; off < 1024; off <<= 1) {
            int t = (tx >= off) ? sb[tx - off] : 0;
            __syncthreads();
            sb[tx] += t;
            __syncthreads();
        }
        if (i < NN) row_ptr[i + 1] = run + sb[tx];
        run += sb[1023];
        __syncthreads();
    }
}

__global__ void pre_build(const int* __restrict__ src, const int* __restrict__ dst,
                          const float* __restrict__ ea, const int* __restrict__ row_ptr,
                          int* __restrict__ cursor, const float* __restrict__ dis_enc,
                          const float* __restrict__ dis_dec, int* __restrict__ src_s,
                          float* __restrict__ w_enc, float* __restrict__ w_dec) {
    int e = blockIdx.x * 256 + threadIdx.x;
    if (e >= EE) return;
    int s = src[e], d = dst[e];
    int pos = row_ptr[d] + atomicAdd(&cursor[d], 1);
    src_s[pos] = s;
    w_enc[pos] = dis_enc[s] * ea[e] * dis_enc[d];
    w_dec[pos] = dis_dec[s] * dis_dec[d];
}

// ---------------- fp32 -> fp16 conversions ----------------

__global__ void cvt_f2h(const float* __restrict__ src, h16* __restrict__ dst, long n4) {
    long i = (long)blockIdx.x * 256 + threadIdx.x;
    if (i >= n4) return;
    float4 v = ((const float4*)src)[i];
    half4 o = {(h16)v.x, (h16)v.y, (h16)v.z, (h16)v.w};
    ((half4*)dst)[i] = o;
}

// W [K][N] fp32 -> WT [N][K] fp16
__global__ void wcvt(const float* __restrict__ Wsrc, h16* __restrict__ WT, int K, int N) {
    int i = blockIdx.x * 256 + threadIdx.x;
    if (i >= K * N) return;
    int n = i / K, k = i % K;
    WT[i] = (h16)Wsrc[(long)k * N + n];
}

// ---------------- sparse A @ X (CSR, fp16 features, fp32 accumulate) ----------------
// thread handles 4 channels (half4). C4 = channels/4.
template <int C4, bool BIAS, bool RELU, bool OUT32>
__global__ __launch_bounds__(256) void spmm_h(
    const h16* __restrict__ in, void* __restrict__ outv,
    const int* __restrict__ rp, const int* __restrict__ srcs,
    const float* __restrict__ w, const float* __restrict__ selfw,
    const float* __restrict__ bias, long sIn, long sOut) {
    const half4* in4 = (const half4*)(in + (long)blockIdx.z * sIn);
    constexpr int NPB = 256 / C4;
    int node = blockIdx.x * NPB + threadIdx.x / C4;
    int c4 = threadIdx.x % C4;
    if (node >= NN) return;
    half4 sv = in4[(long)node * C4 + c4];
    float sw = selfw[node];
    float a0 = sw * (float)sv.x, a1 = sw * (float)sv.y;
    float a2 = sw * (float)sv.z, a3 = sw * (float)sv.w;
    int j = rp[node], e1 = rp[node + 1];
    for (; j + 1 < e1; j += 2) {
        int sA = srcs[j], sB = srcs[j + 1];
        float wA = w[j], wB = w[j + 1];
        half4 vA = in4[(long)sA * C4 + c4];
        half4 vB = in4[(long)sB * C4 + c4];
        a0 += wA * (float)vA.x; a1 += wA * (float)vA.y;
        a2 += wA * (float)vA.z; a3 += wA * (float)vA.w;
        a0 += wB * (float)vB.x; a1 += wB * (float)vB.y;
        a2 += wB * (float)vB.z; a3 += wB * (float)vB.w;
    }
    if (j < e1) {
        float wA = w[j];
        half4 vA = in4[(long)srcs[j] * C4 + c4];
        a0 += wA * (float)vA.x; a1 += wA * (float)vA.y;
        a2 += wA * (float)vA.z; a3 += wA * (float)vA.w;
    }
    if (BIAS) {
        float4 bv = *(const float4*)&bias[c4 * 4];
        a0 += bv.x; a1 += bv.y; a2 += bv.z; a3 += bv.w;
    }
    if (RELU) {
        a0 = fmaxf(a0, 0.f); a1 = fmaxf(a1, 0.f);
        a2 = fmaxf(a2, 0.f); a3 = fmaxf(a3, 0.f);
    }
    if (OUT32) {
        float4* o = ((float4*)outv) + (long)blockIdx.z * (sOut / 4);
        o[(long)node * C4 + c4] = make_float4(a0, a1, a2, a3);
    } else {
        half4* o = ((half4*)outv) + (long)blockIdx.z * (sOut / 4);
        half4 ov = {(h16)a0, (h16)a1, (h16)a2, (h16)a3};
        o[(long)node * C4 + c4] = ov;
    }
}

// ---------------- fp16 MFMA GEMM: C[M,Nc] = act(A[M,K] @ B + bias) ----------------
// BT is B transposed: [Nc][K] fp16. 64x64 tile per block, BK=32, 4 waves.
// mfma_f32_16x16x32_f16: A frag A[m=lane&15][k=quad*8+j]; B frag B[k=quad*8+j][n=lane&15];
// C/D: col=lane&15, row=quad*4+reg.
template <bool BIAS, bool RELU>
__global__ __launch_bounds__(256) void gemm_h(
    const h16* __restrict__ A, const h16* __restrict__ BT,
    const float* __restrict__ bias, h16* __restrict__ C,
    int M, int Nc, int K, long sA, long sC) {
    A += (long)blockIdx.z * sA;
    C += (long)blockIdx.z * sC;
    __shared__ h16 smem[5120];
    h16* As = smem;          // [64][40] padded
    h16* Bs = smem + 2560;   // [64][40]
    int tid = threadIdx.x;
    int bm = blockIdx.y * 64, bn = blockIdx.x * 64;
    int w = tid >> 6, lane = tid & 63;
    int l15 = lane & 15, quad = lane >> 4;
    int srow = tid >> 2, skseg = (tid & 3) * 8;
    floatx4 acc[4] = {{0, 0, 0, 0}, {0, 0, 0, 0}, {0, 0, 0, 0}, {0, 0, 0, 0}};
    for (int k0 = 0; k0 < K; k0 += 32) {
        half8 av = {};
        if (bm + srow < M) av = *(const half8*)&A[(long)(bm + srow) * K + k0 + skseg];
        *(half8*)&As[srow * 40 + skseg] = av;
        *(half8*)&Bs[srow * 40 + skseg] = *(const half8*)&BT[(long)(bn + srow) * K + k0 + skseg];
        __syncthreads();
        half8 af = *(const half8*)&As[(w * 16 + l15) * 40 + quad * 8];
#pragma unroll
        for (int nt = 0; nt < 4; ++nt) {
            half8 bf = *(const half8*)&Bs[(nt * 16 + l15) * 40 + quad * 8];
            acc[nt] = __builtin_amdgcn_mfma_f32_16x16x32_f16(af, bf, acc[nt], 0, 0, 0);
        }
        __syncthreads();
    }
    // epilogue: bounce through LDS for coalesced fp16 stores
    h16* Cs = smem;  // [64][72] = 9216 halfs? no: 4608 halfs = 9216 B <= 10240 B
#pragma unroll
    for (int nt = 0; nt < 4; ++nt) {
        int col = bn + nt * 16 + l15;
        float b = BIAS ? bias[col] : 0.0f;
#pragma unroll
        for (int r = 0; r < 4; ++r) {
            float v = acc[nt][r] + b;
            if (RELU) v = fmaxf(v, 0.0f);
            Cs[(w * 16 + quad * 4 + r) * 72 + nt * 16 + l15] = (h16)v;
        }
    }
    __syncthreads();
    int orow = tid >> 2, oseg = (tid & 3) * 16;
    if (bm + orow < M) {
        half8 v0 = *(const half8*)&Cs[orow * 72 + oseg];
        half8 v1 = *(const half8*)&Cs[orow * 72 + oseg + 8];
        *(half8*)&C[(long)(bm + orow) * Nc + bn + oseg] = v0;
        *(half8*)&C[(long)(bm + orow) * Nc + bn + oseg + 8] = v1;
    }
}

// ---------------- mean pool over nodes (fp16 in, fp32 out) ----------------
__global__ void col_mean_h(const h16* __restrict__ in, float* __restrict__ pooled, long sIn) {
    const h16* p = in + (long)blockIdx.z * sIn;
    float* pt = pooled + (long)blockIdx.z * HH;
    int c = threadIdx.x;
    int n0 = blockIdx.x * 64;
    int n1 = min(n0 + 64, NN);
    float acc = 0.f;
    for (int n = n0; n < n1; ++n) acc += (float)p[(long)n * HH + c];
    atomicAdd(&pt[c], acc * (1.0f / (float)NN));
}

__global__ void enc_head(const float* __restrict__ pooled, const float* __restrict__ Wfce,
                         const float* __restrict__ bfce, float* __restrict__ z) {
    int t = blockIdx.x, j = threadIdx.x;
    __shared__ float p[HH];
    for (int i = j; i < HH; i += 64) p[i] = pooled[t * HH + i];
    __syncthreads();
    float acc = bfce[j];
    for (int h = 0; h < HH; ++h) acc += p[h] * Wfce[h * LL + j];
    z[t * LL + j] = acc;
}

template <int IN>
__global__ void lstm_pre(const float* __restrict__ in, const float* __restrict__ Wih,
                         const float* __restrict__ b1, const float* __restrict__ b2,
                         float* __restrict__ G) {
    int t = blockIdx.y;
    int j = blockIdx.x * 256 + threadIdx.x;
    __shared__ float xs_[IN];
    for (int i = threadIdx.x; i < IN; i += 256) xs_[i] = in[t * IN + i];
    __syncthreads();
    float acc = b1[j] + b2[j];
    for (int k = 0; k < IN; ++k) acc += xs_[k] * Wih[k * 1024 + j];
    G[t * 1024 + j] = acc;
}

__global__ void lstm_step(const float* __restrict__ h_in, float* __restrict__ h_out,
                          float* __restrict__ c, const float* __restrict__ Gt,
                          const float* __restrict__ Whh, float* __restrict__ seq_out) {
    __shared__ float hs[HLL];
    __shared__ float gb[256];
    int tx = threadIdx.x;
    hs[tx] = h_in[tx];
    __syncthreads();
    int gate = tx >> 6, l = tx & 63;
    int j = gate * HLL + blockIdx.x * 64 + l;
    float acc = Gt[j];
    for (int k = 0; k < HLL; ++k) acc += hs[k] * Whh[k * 1024 + j];
    gb[tx] = acc;
    __syncthreads();
    if (tx < 64) {
        int u = blockIdx.x * 64 + tx;
        float ii = gb[tx], ff = gb[64 + tx], gg = gb[128 + tx], oo = gb[192 + tx];
        float cc = sigm(ff) * c[u] + sigm(ii) * tanhf(gg);
        c[u] = cc;
        float hh = sigm(oo) * tanhf(cc);
        h_out[u] = hh;
        if (seq_out) seq_out[u] = hh;
    }
}

__global__ void lstm_head(const float* __restrict__ h, const float* __restrict__ Whead,
                          const float* __restrict__ bhead, float* __restrict__ z) {
    int j = threadIdx.x;
    __shared__ float hs[HLL];
    for (int i = j; i < HLL; i += 64) hs[i] = h[i];
    __syncthreads();
    float acc = bhead[j];
    for (int k = 0; k < HLL; ++k) acc += hs[k] * Whead[k * LL + j];
    z[j] = acc;
}

// Xd = relu(z @ Wfcd + bfcd), fp16 out
__global__ void dec_fc(const float* __restrict__ z, const float* __restrict__ Wfcd,
                       const float* __restrict__ bfcd, h16* __restrict__ Xd) {
    __shared__ float zs_[LL];
    if (threadIdx.x < LL) zs_[threadIdx.x] = z[threadIdx.x];
    __syncthreads();
    long m = ((long)blockIdx.x * 256 + threadIdx.x) * 4;
    if (m >= (long)NN * LL) return;
    float4 acc = *(const float4*)&bfcd[m];
#pragma unroll
    for (int k = 0; k < LL; ++k) {
        float4 w4 = *(const float4*)&Wfcd[(long)k * (NN * (long)LL) + m];
        float zk = zs_[k];
        acc.x += zk * w4.x; acc.y += zk * w4.y; acc.z += zk * w4.z; acc.w += zk * w4.w;
    }
    half4 o = {(h16)fmaxf(acc.x, 0.f), (h16)fmaxf(acc.y, 0.f),
               (h16)fmaxf(acc.z, 0.f), (h16)fmaxf(acc.w, 0.f)};
    *(half4*)&Xd[m] = o;
}

// ---------------- host ----------------

extern "C" void kernel_launch(void* const* d_in, const int* in_sizes, int n_in,
                              void* d_out, int out_size, void* d_ws, size_t ws_size,
                              hipStream_t stream) {
    const float* xs = (const float*)d_in[0];
    const float* edge_attr = (const float*)d_in[1];
    const float* We0 = (const float*)d_in[2];  const float* be0 = (const float*)d_in[3];
    const float* We1 = (const float*)d_in[4];  const float* be1 = (const float*)d_in[5];
    const float* Wfce = (const float*)d_in[6]; const float* bfce = (const float*)d_in[7];
    const float* Wih0 = (const float*)d_in[8]; const float* Whh0 = (const float*)d_in[9];
    const float* bih0 = (const float*)d_in[10]; const float* bhh0 = (const float*)d_in[11];
    const float* Wih1 = (const float*)d_in[12]; const float* Whh1 = (const float*)d_in[13];
    const float* bih1 = (const float*)d_in[14]; const float* bhh1 = (const float*)d_in[15];
    const float* Whead = (const float*)d_in[16]; const float* bhead = (const float*)d_in[17];
    const float* Wfcd = (const float*)d_in[18]; const float* bfcd = (const float*)d_in[19];
    const float* Wd0 = (const float*)d_in[20]; const float* bd0 = (const float*)d_in[21];
    const float* Wd1 = (const float*)d_in[22]; const float* bd1 = (const float*)d_in[23];
    const float* Wd2 = (const float*)d_in[24]; const float* bd2 = (const float*)d_in[25];
    const int* eidx = (const int*)d_in[26];
    const int* esrc = eidx;
    const int* edst = eidx + EE;
    float* out = (float*)d_out;
    float* W = (float*)d_ws;

    // ---- fp32 workspace (float offsets) ----
    const long O_DEG = 0;
    const long O_CNT = 10000;
    const long O_CUR = 20000;
    const long O_POOL = 30000;      // 16*256
    const long O_LSTM = 34096;      // 6*256
    const long ZFLOATS = 36000;
    const long O_DISE = 36000, O_DISD = 46000, O_SNE = 56000, O_SND = 66000;
    const long O_RP = 76000;        // 10016 ints
    const long O_SRCS = 86016;      // 320000 ints
    const long O_WENC = 406016;
    const long O_WDEC = 726016;
    const long O_ZENC = 1046016;    // 16*64
    const long O_G0 = 1047040;      // 16*1024
    const long O_G1 = 1063424;
    const long O_H1S = 1079808;     // 16*256
    const long O_ZDEC = 1083904;    // 64 + pad
    const long O_F16 = 1084000;     // byte offset 4,336,000 (16B aligned)

    // ---- fp16 workspace (half offsets from Hbase) ----
    h16* Hbase = (h16*)(W + O_F16);
    const long HO_XS = 0;                       // 16*10000*128 = 20,480,000
    const long HO_WE0T = 20480000;              // 32768
    const long HO_WE1T = HO_WE0T + 32768;       // 65536
    const long HO_WD0T = HO_WE1T + 65536;       // 16384
    const long HO_WD1T = HO_WD0T + 16384;       // 65536
    const long HO_WD2T = HO_WD1T + 65536;       // 32768
    const long HO_XD = HO_WD2T + 32768;         // 640,000
    const long HO_B0 = HO_XD + 640000;          // 21,332,992

    const long SB0 = (long)NN * FF;   // halfs per timestep, 1,280,000
    const long SB1 = (long)NN * HH;   // 2,560,000

    const long needBatched = O_F16 * 4 + (HO_B0 + 16L * (SB0 + 2 * SB1)) * 2;
    const bool batched = (long)ws_size >= needBatched;
    const long tb = batched ? 16 : 1;
    const long hoB1 = HO_B0 + tb * SB0;
    const long hoB2 = hoB1 + tb * SB1;

    float* deg = W + O_DEG;
    int* cnt = (int*)(W + O_CNT);
    int* cur = (int*)(W + O_CUR);
    float* pooled = W + O_POOL;
    float* h0A = W + O_LSTM; float* h0B = h0A + 256; float* c0 = h0B + 256;
    float* h1A = c0 + 256;   float* h1B = h1A + 256; float* c1 = h1B + 256;
    float* dise = W + O_DISE; float* disd = W + O_DISD;
    float* sne = W + O_SNE;   float* snd = W + O_SND;
    int* rp = (int*)(W + O_RP);
    int* srcs = (int*)(W + O_SRCS);
    float* wenc = W + O_WENC; float* wdec = W + O_WDEC;
    float* zenc = W + O_ZENC; float* G0 = W + O_G0; float* G1 = W + O_G1;
    float* H1seq = W + O_H1S; float* zdec = W + O_ZDEC;
    h16* xsh = Hbase + HO_XS;
    h16* We0T = Hbase + HO_WE0T; h16* We1T = Hbase + HO_WE1T;
    h16* Wd0T = Hbase + HO_WD0T; h16* Wd1T = Hbase + HO_WD1T; h16* Wd2T = Hbase + HO_WD2T;
    h16* XDh = Hbase + HO_XD;
    h16* B0h = Hbase + HO_B0; h16* B1h = Hbase + hoB1; h16* B2h = Hbase + hoB2;

    // ---- preprocessing ----
    hipMemsetAsync(d_ws, 0, ZFLOATS * 4, stream);
    pre_deg<<<(EE + 255) / 256, 256, 0, stream>>>(esrc, edst, edge_attr, deg, cnt);
    pre_dis<<<(NN + 255) / 256, 256, 0, stream>>>(deg, cnt, dise, disd, sne, snd);
    scan_rowptr<<<1, 1024, 0, stream>>>(cnt, rp);
    pre_build<<<(EE + 255) / 256, 256, 0, stream>>>(esrc, edst, edge_attr, rp, cur, dise, disd,
                                                    srcs, wenc, wdec);
    // conversions
    cvt_f2h<<<20000, 256, 0, stream>>>(xs, xsh, (long)TT * NN * FF / 4);
    wcvt<<<(FF * HH + 255) / 256, 256, 0, stream>>>(We0, We0T, FF, HH);
    wcvt<<<(HH * HH + 255) / 256, 256, 0, stream>>>(We1, We1T, HH, HH);
    wcvt<<<(LL * HH + 255) / 256, 256, 0, stream>>>(Wd0, Wd0T, LL, HH);
    wcvt<<<(HH * HH + 255) / 256, 256, 0, stream>>>(Wd1, Wd1T, HH, HH);
    wcvt<<<(HH * FF + 255) / 256, 256, 0, stream>>>(Wd2, Wd2T, HH, FF);

    // ---- encoder ----
    if (batched) {
        spmm_h<32, false, false, false><<<dim3(1250, 1, 16), 256, 0, stream>>>(
            xsh, B0h, rp, srcs, wenc, sne, nullptr, SB0, SB0);
        gemm_h<true, true><<<dim3(4, 157, 16), 256, 0, stream>>>(
            B0h, We0T, be0, B1h, NN, HH, FF, SB0, SB1);
        gemm_h<false, false><<<dim3(4, 157, 16), 256, 0, stream>>>(
            B1h, We1T, nullptr, B2h, NN, HH, HH, SB1, SB1);
        spmm_h<64, true, true, false><<<dim3(2500, 1, 16), 256, 0, stream>>>(
            B2h, B1h, rp, srcs, wenc, sne, be1, SB1, SB1);
        col_mean_h<<<dim3(157, 1, 16), 256, 0, stream>>>(B1h, pooled, SB1);
    } else {
        for (int t = 0; t < TT; ++t) {
            spmm_h<32, false, false, false><<<dim3(1250, 1, 1), 256, 0, stream>>>(
                xsh + (long)t * SB0, B0h, rp, srcs, wenc, sne, nullptr, 0, 0);
            gemm_h<true, true><<<dim3(4, 157, 1), 256, 0, stream>>>(
                B0h, We0T, be0, B1h, NN, HH, FF, 0, 0);
            gemm_h<false, false><<<dim3(4, 157, 1), 256, 0, stream>>>(
                B1h, We1T, nullptr, B2h, NN, HH, HH, 0, 0);
            spmm_h<64, true, true, false><<<dim3(2500, 1, 1), 256, 0, stream>>>(
                B2h, B1h, rp, srcs, wenc, sne, be1, 0, 0);
            col_mean_h<<<dim3(157, 1, 1), 256, 0, stream>>>(B1h, pooled + t * HH, 0);
        }
    }
    enc_head<<<16, 64, 0, stream>>>(pooled, Wfce, bfce, zenc);

    // ---- LSTM (fp32, unchanged) ----
    lstm_pre<64><<<dim3(4, 16), 256, 0, stream>>>(zenc, Wih0, bih0, bhh0, G0);
    {
        float* hi = h0A; float* ho = h0B;
        for (int t = 0; t < TT; ++t) {
            lstm_step<<<4, 256, 0, stream>>>(hi, ho, c0, G0 + t * 1024, Whh0, H1seq + t * HLL);
            float* tmp = hi; hi = ho; ho = tmp;
        }
    }
    lstm_pre<256><<<dim3(4, 16), 256, 0, stream>>>(H1seq, Wih1, bih1, bhh1, G1);
    float* hfinal;
    {
        float* hi = h1A; float* ho = h1B;
        for (int t = 0; t < TT; ++t) {
            lstm_step<<<4, 256, 0, stream>>>(hi, ho, c1, G1 + t * 1024, Whh1, nullptr);
            float* tmp = hi; hi = ho; ho = tmp;
        }
        hfinal = hi;
    }
    lstm_head<<<1, 64, 0, stream>>>(hfinal, Whead, bhead, zdec);

    // ---- decoder ----
    dec_fc<<<625, 256, 0, stream>>>(zdec, Wfcd, bfcd, XDh);
    spmm_h<16, false, false, false><<<dim3(625, 1, 1), 256, 0, stream>>>(
        XDh, B0h, rp, srcs, wdec, snd, nullptr, 0, 0);
    gemm_h<true, true><<<dim3(4, 157, 1), 256, 0, stream>>>(
        B0h, Wd0T, bd0, B1h, NN, HH, LL, 0, 0);
    gemm_h<false, false><<<dim3(4, 157, 1), 256, 0, stream>>>(
        B1h, Wd1T, nullptr, B2h, NN, HH, HH, 0, 0);
    spmm_h<64, true, true, false><<<dim3(2500, 1, 1), 256, 0, stream>>>(
        B2h, B1h, rp, srcs, wdec, snd, bd1, 0, 0);
    gemm_h<false, false><<<dim3(2, 157, 1), 256, 0, stream>>>(
        B1h, Wd2T, nullptr, B0h, NN, FF, HH, 0, 0);
    spmm_h<32, true, false, true><<<dim3(1250, 1, 1), 256, 0, stream>>>(
        B0h, out, rp, srcs, wdec, snd, bd2, 0, 0);
}

// Round 3
// 1150.815 us; speedup vs baseline: 2.4603x; 1.2440x over previous
//
#include <hip/hip_runtime.h>
#include <math.h>

#define TT 16
#define NN 10000
#define EE 320000
#define FF 128
#define HH 256
#define LL 64
#define HLL 256

typedef _Float16 h16;
typedef _Float16 half4 __attribute__((ext_vector_type(4)));
typedef _Float16 half8 __attribute__((ext_vector_type(8)));
typedef float floatx4 __attribute__((ext_vector_type(4)));

__device__ __forceinline__ float sigm(float x) { return 1.0f / (1.0f + expf(-x)); }

// ---------------- preprocessing ----------------

__global__ void pre_deg(const int* __restrict__ src, const int* __restrict__ dst,
                        const float* __restrict__ ea, float* __restrict__ deg_enc,
                        int* __restrict__ cnt) {
    int e = blockIdx.x * 256 + threadIdx.x;
    if (e >= EE) return;
    int d = dst[e];
    atomicAdd(&deg_enc[d], ea[e]);
    atomicAdd(&cnt[d], 1);
}

__global__ void pre_dis(const float* __restrict__ deg_enc, const int* __restrict__ cnt,
                        float* __restrict__ dis_enc, float* __restrict__ dis_dec,
                        float* __restrict__ sn_enc, float* __restrict__ sn_dec) {
    int n = blockIdx.x * 256 + threadIdx.x;
    if (n >= NN) return;
    float de = deg_enc[n] + 1.0f;
    float dd = (float)cnt[n] + 1.0f;
    dis_enc[n] = rsqrtf(de);
    dis_dec[n] = rsqrtf(dd);
    sn_enc[n] = 1.0f / de;
    sn_dec[n] = 1.0f / dd;
}

__global__ void scan_rowptr(const int* __restrict__ cnt, int* __restrict__ row_ptr) {
    __shared__ int sb[1024];
    int tx = threadIdx.x;
    int run = 0;
    if (tx == 0) row_ptr[0] = 0;
    for (int base = 0; base < NN; base += 1024) {
        int i = base + tx;
        int v = (i < NN) ? cnt[i] : 0;
        sb[tx] = v;
        __syncthreads();
        for (int off = 1; off < 1024; off <<= 1) {
            int t = (tx >= off) ? sb[tx - off] : 0;
            __syncthreads();
            sb[tx] += t;
            __syncthreads();
        }
        if (i < NN) row_ptr[i + 1] = run + sb[tx];
        run += sb[1023];
        __syncthreads();
    }
}

__global__ void pre_build(const int* __restrict__ src, const int* __restrict__ dst,
                          const float* __restrict__ ea, const int* __restrict__ row_ptr,
                          int* __restrict__ cursor, const float* __restrict__ dis_enc,
                          const float* __restrict__ dis_dec, int* __restrict__ src_s,
                          float* __restrict__ w_enc, float* __restrict__ w_dec) {
    int e = blockIdx.x * 256 + threadIdx.x;
    if (e >= EE) return;
    int s = src[e], d = dst[e];
    int pos = row_ptr[d] + atomicAdd(&cursor[d], 1);
    src_s[pos] = s;
    w_enc[pos] = dis_enc[s] * ea[e] * dis_enc[d];
    w_dec[pos] = dis_dec[s] * dis_dec[d];
}

// ---------------- fp32 -> fp16 conversions ----------------

__global__ void cvt_f2h(const float* __restrict__ src, h16* __restrict__ dst, long n4) {
    long i = (long)blockIdx.x * 256 + threadIdx.x;
    if (i >= n4) return;
    float4 v = ((const float4*)src)[i];
    half4 o = {(h16)v.x, (h16)v.y, (h16)v.z, (h16)v.w};
    ((half4*)dst)[i] = o;
}

// W [K][N] fp32 -> WT [N][K] fp16
__global__ void wcvt(const float* __restrict__ Wsrc, h16* __restrict__ WT, int K, int N) {
    int i = blockIdx.x * 256 + threadIdx.x;
    if (i >= K * N) return;
    int n = i / K, k = i % K;
    WT[i] = (h16)Wsrc[(long)k * N + n];
}

// ---------------- sparse A @ X, multi-edge-per-wave (CSR, fp16 feats, fp32 acc) ----
// LPE lanes cover one edge's channels (LPE*8 = C). EPW = 64/LPE edges in parallel.
// Wave = 1 node (4 nodes/block). Edge-group partials combined via shfl_xor tree.
template <int LPE, bool BIAS, bool RELU, bool OUT32>
__global__ __launch_bounds__(256) void spmm2(
    const h16* __restrict__ in, void* __restrict__ outv,
    const int* __restrict__ rp, const int* __restrict__ srcs,
    const float* __restrict__ w, const float* __restrict__ selfw,
    const float* __restrict__ bias, long sIn, long sOut) {
    constexpr int EPW = 64 / LPE;
    const half8* in8 = (const half8*)(in + (long)blockIdx.z * sIn);
    int wv = threadIdx.x >> 6;
    int node = blockIdx.x * 4 + wv;
    int lane = threadIdx.x & 63;
    int c8 = lane & (LPE - 1);
    int el = lane / LPE;
    float acc[8] = {0.f, 0.f, 0.f, 0.f, 0.f, 0.f, 0.f, 0.f};
    if (el == 0) {
        half8 sv = in8[(long)node * LPE + c8];
        float sw = selfw[node];
#pragma unroll
        for (int i = 0; i < 8; ++i) acc[i] = sw * (float)sv[i];
    }
    int r1 = rp[node + 1];
    int j = rp[node] + el;
    for (; j + EPW < r1; j += 2 * EPW) {
        int sA = srcs[j], sB = srcs[j + EPW];
        float wA = w[j], wB = w[j + EPW];
        half8 vA = in8[(long)sA * LPE + c8];
        half8 vB = in8[(long)sB * LPE + c8];
#pragma unroll
        for (int i = 0; i < 8; ++i) acc[i] += wA * (float)vA[i] + wB * (float)vB[i];
    }
    if (j < r1) {
        float wA = w[j];
        half8 vA = in8[(long)srcs[j] * LPE + c8];
#pragma unroll
        for (int i = 0; i < 8; ++i) acc[i] += wA * (float)vA[i];
    }
#pragma unroll
    for (int m = LPE; m < 64; m <<= 1) {
#pragma unroll
        for (int i = 0; i < 8; ++i) acc[i] += __shfl_xor(acc[i], m);
    }
    if (el == 0) {
        if (BIAS) {
            float4 b0 = *(const float4*)&bias[c8 * 8];
            float4 b1 = *(const float4*)&bias[c8 * 8 + 4];
            acc[0] += b0.x; acc[1] += b0.y; acc[2] += b0.z; acc[3] += b0.w;
            acc[4] += b1.x; acc[5] += b1.y; acc[6] += b1.z; acc[7] += b1.w;
        }
        if (RELU) {
#pragma unroll
            for (int i = 0; i < 8; ++i) acc[i] = fmaxf(acc[i], 0.f);
        }
        if (OUT32) {
            float* o = (float*)outv + (long)blockIdx.z * sOut + (long)node * (LPE * 8) + c8 * 8;
            *(float4*)o = make_float4(acc[0], acc[1], acc[2], acc[3]);
            *(float4*)(o + 4) = make_float4(acc[4], acc[5], acc[6], acc[7]);
        } else {
            half8 ov = {(h16)acc[0], (h16)acc[1], (h16)acc[2], (h16)acc[3],
                        (h16)acc[4], (h16)acc[5], (h16)acc[6], (h16)acc[7]};
            ((half8*)((h16*)outv + (long)blockIdx.z * sOut))[(long)node * LPE + c8] = ov;
        }
    }
}

// ---------------- fp16 MFMA GEMM: C[M,Nc] = act(A[M,K] @ B + bias) ----------------
template <bool BIAS, bool RELU>
__global__ __launch_bounds__(256) void gemm_h(
    const h16* __restrict__ A, const h16* __restrict__ BT,
    const float* __restrict__ bias, h16* __restrict__ C,
    int M, int Nc, int K, long sA, long sC) {
    A += (long)blockIdx.z * sA;
    C += (long)blockIdx.z * sC;
    __shared__ h16 smem[5120];
    h16* As = smem;          // [64][40] padded
    h16* Bs = smem + 2560;   // [64][40]
    int tid = threadIdx.x;
    int bm = blockIdx.y * 64, bn = blockIdx.x * 64;
    int w = tid >> 6, lane = tid & 63;
    int l15 = lane & 15, quad = lane >> 4;
    int srow = tid >> 2, skseg = (tid & 3) * 8;
    floatx4 acc[4] = {{0, 0, 0, 0}, {0, 0, 0, 0}, {0, 0, 0, 0}, {0, 0, 0, 0}};
    for (int k0 = 0; k0 < K; k0 += 32) {
        half8 av = {};
        if (bm + srow < M) av = *(const half8*)&A[(long)(bm + srow) * K + k0 + skseg];
        *(half8*)&As[srow * 40 + skseg] = av;
        *(half8*)&Bs[srow * 40 + skseg] = *(const half8*)&BT[(long)(bn + srow) * K + k0 + skseg];
        __syncthreads();
        half8 af = *(const half8*)&As[(w * 16 + l15) * 40 + quad * 8];
#pragma unroll
        for (int nt = 0; nt < 4; ++nt) {
            half8 bf = *(const half8*)&Bs[(nt * 16 + l15) * 40 + quad * 8];
            acc[nt] = __builtin_amdgcn_mfma_f32_16x16x32_f16(af, bf, acc[nt], 0, 0, 0);
        }
        __syncthreads();
    }
    h16* Cs = smem;
#pragma unroll
    for (int nt = 0; nt < 4; ++nt) {
        int col = bn + nt * 16 + l15;
        float b = BIAS ? bias[col] : 0.0f;
#pragma unroll
        for (int r = 0; r < 4; ++r) {
            float v = acc[nt][r] + b;
            if (RELU) v = fmaxf(v, 0.0f);
            Cs[(w * 16 + quad * 4 + r) * 72 + nt * 16 + l15] = (h16)v;
        }
    }
    __syncthreads();
    int orow = tid >> 2, oseg = (tid & 3) * 16;
    if (bm + orow < M) {
        half8 v0 = *(const half8*)&Cs[orow * 72 + oseg];
        half8 v1 = *(const half8*)&Cs[orow * 72 + oseg + 8];
        *(half8*)&C[(long)(bm + orow) * Nc + bn + oseg] = v0;
        *(half8*)&C[(long)(bm + orow) * Nc + bn + oseg + 8] = v1;
    }
}

// ---------------- mean pool over nodes (fp16 in, fp32 out) ----------------
__global__ void col_mean_h(const h16* __restrict__ in, float* __restrict__ pooled, long sIn) {
    const h16* p = in + (long)blockIdx.z * sIn;
    float* pt = pooled + (long)blockIdx.z * HH;
    int c = threadIdx.x;
    int n0 = blockIdx.x * 64;
    int n1 = min(n0 + 64, NN);
    float acc = 0.f;
    for (int n = n0; n < n1; ++n) acc += (float)p[(long)n * HH + c];
    atomicAdd(&pt[c], acc * (1.0f / (float)NN));
}

__global__ void enc_head(const float* __restrict__ pooled, const float* __restrict__ Wfce,
                         const float* __restrict__ bfce, float* __restrict__ z) {
    int t = blockIdx.x, j = threadIdx.x;
    __shared__ float p[HH];
    for (int i = j; i < HH; i += 64) p[i] = pooled[t * HH + i];
    __syncthreads();
    float acc = bfce[j];
    for (int h = 0; h < HH; ++h) acc += p[h] * Wfce[h * LL + j];
    z[t * LL + j] = acc;
}

// ---------------- fused 2-layer LSTM + head, persistent 16-block kernel ----------
// Block b owns units [b*16, b*16+16) (all 4 gates = 64 gate-cols).
// Whh slice in LDS fp16; G precomputed per layer in LDS; device spin-barrier/step.
__global__ __launch_bounds__(256) void fused_lstm(
    const float* __restrict__ zenc,
    const float* __restrict__ Wih0, const float* __restrict__ Whh0,
    const float* __restrict__ bih0, const float* __restrict__ bhh0,
    const float* __restrict__ Wih1, const float* __restrict__ Whh1,
    const float* __restrict__ bih1, const float* __restrict__ bhh1,
    const float* __restrict__ Whead, const float* __restrict__ bhead,
    float* __restrict__ H1, float* __restrict__ H2,   // [17][256], row0 zeroed
    unsigned* __restrict__ bar, float* __restrict__ zdec) {
    __shared__ h16 Ws[256][64];
    __shared__ float Gs[16][64];
    __shared__ float part[4][64];
    __shared__ float hbuf[256];
    __shared__ float cbuf[16];
    int tid = threadIdx.x;
    int kq = tid >> 6;            // wave id = k-quarter
    int col = tid & 63;           // gate-col within block: g4*16 + ul
    int g4 = col >> 4, ul = col & 15;
    int u0 = blockIdx.x * 16;
    int jg = g4 * 256 + u0 + ul;  // global gate index
    unsigned gen = 0;

#define GBAR()                                                        \
    do {                                                              \
        __threadfence();                                              \
        __syncthreads();                                              \
        if (tid == 0) {                                               \
            ++gen;                                                    \
            atomicAdd(bar, 1u);                                       \
            while (atomicAdd(bar, 0u) < 16u * gen)                    \
                __builtin_amdgcn_s_sleep(2);                          \
        }                                                             \
        __syncthreads();                                              \
        __threadfence();                                              \
    } while (0)

    // ---- layer 1 setup ----
    if (tid < 16) cbuf[tid] = 0.f;
    for (int idx = tid; idx < 256 * 64; idx += 256) {
        int k = idx >> 6, c = idx & 63;
        Ws[k][c] = (h16)Whh0[k * 1024 + (c >> 4) * 256 + u0 + (c & 15)];
    }
    {
        float b = bih0[jg] + bhh0[jg];
        float a0 = b, a1 = b, a2 = b, a3 = b;
        for (int k = 0; k < 64; ++k) {
            float wvv = Wih0[k * 1024 + jg];
            a0 += zenc[kq * 64 + k] * wvv;
            a1 += zenc[(kq + 4) * 64 + k] * wvv;
            a2 += zenc[(kq + 8) * 64 + k] * wvv;
            a3 += zenc[(kq + 12) * 64 + k] * wvv;
        }
        Gs[kq][col] = a0; Gs[kq + 4][col] = a1;
        Gs[kq + 8][col] = a2; Gs[kq + 12][col] = a3;
    }
    __syncthreads();
    // ---- layer 1 steps ----
    for (int t = 1; t <= 16; ++t) {
        hbuf[tid] = H1[(t - 1) * 256 + tid];
        __syncthreads();
        float acc = 0.f;
#pragma unroll
        for (int i = 0; i < 64; ++i) acc += hbuf[kq * 64 + i] * (float)Ws[kq * 64 + i][col];
        part[kq][col] = acc;
        __syncthreads();
        if (tid < 16) {
            int u = tid;
            float i_ = Gs[t - 1][u]      + part[0][u]      + part[1][u]      + part[2][u]      + part[3][u];
            float f_ = Gs[t - 1][16 + u] + part[0][16 + u] + part[1][16 + u] + part[2][16 + u] + part[3][16 + u];
            float g_ = Gs[t - 1][32 + u] + part[0][32 + u] + part[1][32 + u] + part[2][32 + u] + part[3][32 + u];
            float o_ = Gs[t - 1][48 + u] + part[0][48 + u] + part[1][48 + u] + part[2][48 + u] + part[3][48 + u];
            float cc = sigm(f_) * cbuf[u] + sigm(i_) * tanhf(g_);
            cbuf[u] = cc;
            H1[t * 256 + u0 + u] = sigm(o_) * tanhf(cc);
        }
        GBAR();
    }
    // ---- layer 2 setup ----
    if (tid < 16) cbuf[tid] = 0.f;
    for (int idx = tid; idx < 256 * 64; idx += 256) {
        int k = idx >> 6, c = idx & 63;
        Ws[k][c] = (h16)Whh1[k * 1024 + (c >> 4) * 256 + u0 + (c & 15)];
    }
    {
        float b = bih1[jg] + bhh1[jg];
        float a0 = b, a1 = b, a2 = b, a3 = b;
        for (int k = 0; k < 256; ++k) {
            float wvv = Wih1[k * 1024 + jg];
            a0 += H1[(kq + 1) * 256 + k] * wvv;
            a1 += H1[(kq + 5) * 256 + k] * wvv;
            a2 += H1[(kq + 9) * 256 + k] * wvv;
            a3 += H1[(kq + 13) * 256 + k] * wvv;
        }
        Gs[kq][col] = a0; Gs[kq + 4][col] = a1;
        Gs[kq + 8][col] = a2; Gs[kq + 12][col] = a3;
    }
    __syncthreads();
    // ---- layer 2 steps ----
    for (int t = 1; t <= 16; ++t) {
        hbuf[tid] = H2[(t - 1) * 256 + tid];
        __syncthreads();
        float acc = 0.f;
#pragma unroll
        for (int i = 0; i < 64; ++i) acc += hbuf[kq * 64 + i] * (float)Ws[kq * 64 + i][col];
        part[kq][col] = acc;
        __syncthreads();
        if (tid < 16) {
            int u = tid;
            float i_ = Gs[t - 1][u]      + part[0][u]      + part[1][u]      + part[2][u]      + part[3][u];
            float f_ = Gs[t - 1][16 + u] + part[0][16 + u] + part[1][16 + u] + part[2][16 + u] + part[3][16 + u];
            float g_ = Gs[t - 1][32 + u] + part[0][32 + u] + part[1][32 + u] + part[2][32 + u] + part[3][32 + u];
            float o_ = Gs[t - 1][48 + u] + part[0][48 + u] + part[1][48 + u] + part[2][48 + u] + part[3][48 + u];
            float cc = sigm(f_) * cbuf[u] + sigm(i_) * tanhf(g_);
            cbuf[u] = cc;
            H2[t * 256 + u0 + u] = sigm(o_) * tanhf(cc);
        }
        GBAR();
    }
    // ---- head ----
    if (blockIdx.x == 0 && tid < 64) {
        const float* hf = H2 + 16 * 256;
        float a = bhead[tid];
        for (int k = 0; k < 256; ++k) a += hf[k] * Whead[k * 64 + tid];
        zdec[tid] = a;
    }
#undef GBAR
}

// Xd = relu(z @ Wfcd + bfcd), fp16 out
__global__ void dec_fc(const float* __restrict__ z, const float* __restrict__ Wfcd,
                       const float* __restrict__ bfcd, h16* __restrict__ Xd) {
    __shared__ float zs_[LL];
    if (threadIdx.x < LL) zs_[threadIdx.x] = z[threadIdx.x];
    __syncthreads();
    long m = ((long)blockIdx.x * 256 + threadIdx.x) * 4;
    if (m >= (long)NN * LL) return;
    float4 acc = *(const float4*)&bfcd[m];
#pragma unroll
    for (int k = 0; k < LL; ++k) {
        float4 w4 = *(const float4*)&Wfcd[(long)k * (NN * (long)LL) + m];
        float zk = zs_[k];
        acc.x += zk * w4.x; acc.y += zk * w4.y; acc.z += zk * w4.z; acc.w += zk * w4.w;
    }
    half4 o = {(h16)fmaxf(acc.x, 0.f), (h16)fmaxf(acc.y, 0.f),
               (h16)fmaxf(acc.z, 0.f), (h16)fmaxf(acc.w, 0.f)};
    *(half4*)&Xd[m] = o;
}

// ---------------- host ----------------

extern "C" void kernel_launch(void* const* d_in, const int* in_sizes, int n_in,
                              void* d_out, int out_size, void* d_ws, size_t ws_size,
                              hipStream_t stream) {
    const float* xs = (const float*)d_in[0];
    const float* edge_attr = (const float*)d_in[1];
    const float* We0 = (const float*)d_in[2];  const float* be0 = (const float*)d_in[3];
    const float* We1 = (const float*)d_in[4];  const float* be1 = (const float*)d_in[5];
    const float* Wfce = (const float*)d_in[6]; const float* bfce = (const float*)d_in[7];
    const float* Wih0 = (const float*)d_in[8]; const float* Whh0 = (const float*)d_in[9];
    const float* bih0 = (const float*)d_in[10]; const float* bhh0 = (const float*)d_in[11];
    const float* Wih1 = (const float*)d_in[12]; const float* Whh1 = (const float*)d_in[13];
    const float* bih1 = (const float*)d_in[14]; const float* bhh1 = (const float*)d_in[15];
    const float* Whead = (const float*)d_in[16]; const float* bhead = (const float*)d_in[17];
    const float* Wfcd = (const float*)d_in[18]; const float* bfcd = (const float*)d_in[19];
    const float* Wd0 = (const float*)d_in[20]; const float* bd0 = (const float*)d_in[21];
    const float* Wd1 = (const float*)d_in[22]; const float* bd1 = (const float*)d_in[23];
    const float* Wd2 = (const float*)d_in[24]; const float* bd2 = (const float*)d_in[25];
    const int* eidx = (const int*)d_in[26];
    const int* esrc = eidx;
    const int* edst = eidx + EE;
    float* out = (float*)d_out;
    float* W = (float*)d_ws;

    // ---- fp32 workspace (float offsets) ----
    // zeroed region:
    const long O_DEG = 0;            // [10000]
    const long O_CNT = 10000;        // [10000] i32
    const long O_CUR = 20000;        // [10000] i32
    const long O_POOL = 30000;       // [16*256]
    const long O_H1 = 34096;         // [17*256]
    const long O_H2 = 38448;         // [17*256]
    const long O_BAR = 42800;        // [16]
    const long ZFLOATS = 42816;
    // non-zeroed:
    const long O_DISE = 42816, O_DISD = 52816, O_SNE = 62816, O_SND = 72816;
    const long O_RP = 82816;         // 10016 ints
    const long O_SRCS = 92832;       // 320000 ints
    const long O_WENC = 412832;
    const long O_WDEC = 732832;
    const long O_ZENC = 1052832;     // 16*64
    const long O_ZDEC = 1053856;     // 64
    const long O_F16 = 1053920;      // 16B-aligned

    h16* Hbase = (h16*)(W + O_F16);
    const long HO_XS = 0;                       // 20,480,000
    const long HO_WE0T = 20480000;
    const long HO_WE1T = HO_WE0T + 32768;
    const long HO_WD0T = HO_WE1T + 65536;
    const long HO_WD1T = HO_WD0T + 16384;
    const long HO_WD2T = HO_WD1T + 65536;
    const long HO_XD = HO_WD2T + 32768;
    const long HO_B0 = HO_XD + 640000;

    const long SB0 = (long)NN * FF;   // 1,280,000 halfs / timestep
    const long SB1 = (long)NN * HH;   // 2,560,000

    const long needBatched = O_F16 * 4 + (HO_B0 + 16L * (SB0 + 2 * SB1)) * 2;
    const bool batched = (long)ws_size >= needBatched;
    const long tb = batched ? 16 : 1;
    const long hoB1 = HO_B0 + tb * SB0;
    const long hoB2 = hoB1 + tb * SB1;

    float* deg = W + O_DEG;
    int* cnt = (int*)(W + O_CNT);
    int* cur = (int*)(W + O_CUR);
    float* pooled = W + O_POOL;
    float* H1 = W + O_H1; float* H2 = W + O_H2;
    unsigned* bar = (unsigned*)(W + O_BAR);
    float* dise = W + O_DISE; float* disd = W + O_DISD;
    float* sne = W + O_SNE;   float* snd = W + O_SND;
    int* rp = (int*)(W + O_RP);
    int* srcs = (int*)(W + O_SRCS);
    float* wenc = W + O_WENC; float* wdec = W + O_WDEC;
    float* zenc = W + O_ZENC; float* zdec = W + O_ZDEC;
    h16* xsh = Hbase + HO_XS;
    h16* We0T = Hbase + HO_WE0T; h16* We1T = Hbase + HO_WE1T;
    h16* Wd0T = Hbase + HO_WD0T; h16* Wd1T = Hbase + HO_WD1T; h16* Wd2T = Hbase + HO_WD2T;
    h16* XDh = Hbase + HO_XD;
    h16* B0h = Hbase + HO_B0; h16* B1h = Hbase + hoB1; h16* B2h = Hbase + hoB2;

    // ---- preprocessing ----
    hipMemsetAsync(d_ws, 0, ZFLOATS * 4, stream);
    pre_deg<<<(EE + 255) / 256, 256, 0, stream>>>(esrc, edst, edge_attr, deg, cnt);
    pre_dis<<<(NN + 255) / 256, 256, 0, stream>>>(deg, cnt, dise, disd, sne, snd);
    scan_rowptr<<<1, 1024, 0, stream>>>(cnt, rp);
    pre_build<<<(EE + 255) / 256, 256, 0, stream>>>(esrc, edst, edge_attr, rp, cur, dise, disd,
                                                    srcs, wenc, wdec);
    cvt_f2h<<<20000, 256, 0, stream>>>(xs, xsh, (long)TT * NN * FF / 4);
    wcvt<<<(FF * HH + 255) / 256, 256, 0, stream>>>(We0, We0T, FF, HH);
    wcvt<<<(HH * HH + 255) / 256, 256, 0, stream>>>(We1, We1T, HH, HH);
    wcvt<<<(LL * HH + 255) / 256, 256, 0, stream>>>(Wd0, Wd0T, LL, HH);
    wcvt<<<(HH * HH + 255) / 256, 256, 0, stream>>>(Wd1, Wd1T, HH, HH);
    wcvt<<<(HH * FF + 255) / 256, 256, 0, stream>>>(Wd2, Wd2T, HH, FF);

    // ---- encoder ----
    if (batched) {
        spmm2<16, false, false, false><<<dim3(2500, 1, 16), 256, 0, stream>>>(
            xsh, B0h, rp, srcs, wenc, sne, nullptr, SB0, SB0);
        gemm_h<true, true><<<dim3(4, 157, 16), 256, 0, stream>>>(
            B0h, We0T, be0, B1h, NN, HH, FF, SB0, SB1);
        gemm_h<false, false><<<dim3(4, 157, 16), 256, 0, stream>>>(
            B1h, We1T, nullptr, B2h, NN, HH, HH, SB1, SB1);
        spmm2<32, true, true, false><<<dim3(2500, 1, 16), 256, 0, stream>>>(
            B2h, B1h, rp, srcs, wenc, sne, be1, SB1, SB1);
        col_mean_h<<<dim3(157, 1, 16), 256, 0, stream>>>(B1h, pooled, SB1);
    } else {
        for (int t = 0; t < TT; ++t) {
            spmm2<16, false, false, false><<<dim3(2500, 1, 1), 256, 0, stream>>>(
                xsh + (long)t * SB0, B0h, rp, srcs, wenc, sne, nullptr, 0, 0);
            gemm_h<true, true><<<dim3(4, 157, 1), 256, 0, stream>>>(
                B0h, We0T, be0, B1h, NN, HH, FF, 0, 0);
            gemm_h<false, false><<<dim3(4, 157, 1), 256, 0, stream>>>(
                B1h, We1T, nullptr, B2h, NN, HH, HH, 0, 0);
            spmm2<32, true, true, false><<<dim3(2500, 1, 1), 256, 0, stream>>>(
                B2h, B1h, rp, srcs, wenc, sne, be1, 0, 0);
            col_mean_h<<<dim3(157, 1, 1), 256, 0, stream>>>(B1h, pooled + t * HH, 0);
        }
    }
    enc_head<<<16, 64, 0, stream>>>(pooled, Wfce, bfce, zenc);

    // ---- fused LSTM (1 launch replaces 35) ----
    fused_lstm<<<16, 256, 0, stream>>>(zenc, Wih0, Whh0, bih0, bhh0,
                                       Wih1, Whh1, bih1, bhh1,
                                       Whead, bhead, H1, H2, bar, zdec);

    // ---- decoder ----
    dec_fc<<<625, 256, 0, stream>>>(zdec, Wfcd, bfcd, XDh);
    spmm2<8, false, false, false><<<dim3(2500, 1, 1), 256, 0, stream>>>(
        XDh, B0h, rp, srcs, wdec, snd, nullptr, 0, 0);
    gemm_h<true, true><<<dim3(4, 157, 1), 256, 0, stream>>>(
        B0h, Wd0T, bd0, B1h, NN, HH, LL, 0, 0);
    gemm_h<false, false><<<dim3(4, 157, 1), 256, 0, stream>>>(
        B1h, Wd1T, nullptr, B2h, NN, HH, HH, 0, 0);
    spmm2<32, true, true, false><<<dim3(2500, 1, 1), 256, 0, stream>>>(
        B2h, B1h, rp, srcs, wdec, snd, bd1, 0, 0);
    gemm_h<false, false><<<dim3(2, 157, 1), 256, 0, stream>>>(
        B1h, Wd2T, nullptr, B0h, NN, FF, HH, 0, 0);
    spmm2<16, true, false, true><<<dim3(2500, 1, 1), 256, 0, stream>>>(
        B0h, out, rp, srcs, wdec, snd, bd2, 0, 0);
}

// Round 4
// 1093.882 us; speedup vs baseline: 2.5883x; 1.0520x over previous
//
#include <hip/hip_runtime.h>
#include <math.h>

#define TT 16
#define NN 10000
#define EE 320000
#define FF 128
#define HH 256
#define LL 64
#define HLL 256

typedef _Float16 h16;
typedef _Float16 half4 __attribute__((ext_vector_type(4)));
typedef _Float16 half8 __attribute__((ext_vector_type(8)));
typedef float floatx4 __attribute__((ext_vector_type(4)));

__device__ __forceinline__ float sigm(float x) { return 1.0f / (1.0f + expf(-x)); }

// ---------------- preprocessing ----------------

__global__ void pre_deg(const int* __restrict__ src, const int* __restrict__ dst,
                        const float* __restrict__ ea, float* __restrict__ deg_enc,
                        int* __restrict__ cnt) {
    int e = blockIdx.x * 256 + threadIdx.x;
    if (e >= EE) return;
    int d = dst[e];
    atomicAdd(&deg_enc[d], ea[e]);
    atomicAdd(&cnt[d], 1);
}

__global__ void pre_dis(const float* __restrict__ deg_enc, const int* __restrict__ cnt,
                        float* __restrict__ dis_enc, float* __restrict__ dis_dec,
                        float* __restrict__ sn_enc, float* __restrict__ sn_dec) {
    int n = blockIdx.x * 256 + threadIdx.x;
    if (n >= NN) return;
    float de = deg_enc[n] + 1.0f;
    float dd = (float)cnt[n] + 1.0f;
    dis_enc[n] = rsqrtf(de);
    dis_dec[n] = rsqrtf(dd);
    sn_enc[n] = 1.0f / de;
    sn_dec[n] = 1.0f / dd;
}

__global__ void scan_rowptr(const int* __restrict__ cnt, int* __restrict__ row_ptr) {
    __shared__ int sb[1024];
    int tx = threadIdx.x;
    int run = 0;
    if (tx == 0) row_ptr[0] = 0;
    for (int base = 0; base < NN; base += 1024) {
        int i = base + tx;
        int v = (i < NN) ? cnt[i] : 0;
        sb[tx] = v;
        __syncthreads();
        for (int off = 1; off < 1024; off <<= 1) {
            int t = (tx >= off) ? sb[tx - off] : 0;
            __syncthreads();
            sb[tx] += t;
            __syncthreads();
        }
        if (i < NN) row_ptr[i + 1] = run + sb[tx];
        run += sb[1023];
        __syncthreads();
    }
}

__global__ void pre_build(const int* __restrict__ src, const int* __restrict__ dst,
                          const float* __restrict__ ea, const int* __restrict__ row_ptr,
                          int* __restrict__ cursor, const float* __restrict__ dis_enc,
                          const float* __restrict__ dis_dec, int* __restrict__ src_s,
                          float* __restrict__ w_enc, float* __restrict__ w_dec) {
    int e = blockIdx.x * 256 + threadIdx.x;
    if (e >= EE) return;
    int s = src[e], d = dst[e];
    int pos = row_ptr[d] + atomicAdd(&cursor[d], 1);
    src_s[pos] = s;
    w_enc[pos] = dis_enc[s] * ea[e] * dis_enc[d];
    w_dec[pos] = dis_dec[s] * dis_dec[d];
}

// ---------------- fp32 -> fp16 conversions ----------------

__global__ void cvt_f2h(const float* __restrict__ src, h16* __restrict__ dst, long n4) {
    long i = (long)blockIdx.x * 256 + threadIdx.x;
    if (i >= n4) return;
    float4 v = ((const float4*)src)[i];
    half4 o = {(h16)v.x, (h16)v.y, (h16)v.z, (h16)v.w};
    ((half4*)dst)[i] = o;
}

// W [K][N] fp32 -> WT [N][K] fp16
__global__ void wcvt(const float* __restrict__ Wsrc, h16* __restrict__ WT, int K, int N) {
    int i = blockIdx.x * 256 + threadIdx.x;
    if (i >= K * N) return;
    int n = i / K, k = i % K;
    WT[i] = (h16)Wsrc[(long)k * N + n];
}

// ---------------- sparse A @ X, multi-edge-per-wave (CSR, fp16 feats, fp32 acc) ----
// LPE lanes cover one edge's channels (LPE*8 = C). EPW = 64/LPE edges in parallel.
// Wave = 1 node (4 nodes/block). 1D grid; for tbatch=16 an XCD-aware swizzle maps
// z = (g%8) + 8*(g/20000) so each XCD's L2 sees ~1 timestep's working set at a time.
template <int LPE, bool BIAS, bool RELU, bool OUT32>
__global__ __launch_bounds__(256) void spmm2(
    const h16* __restrict__ in, void* __restrict__ outv,
    const int* __restrict__ rp, const int* __restrict__ srcs,
    const float* __restrict__ w, const float* __restrict__ selfw,
    const float* __restrict__ bias, long sIn, long sOut, int tbatch) {
    constexpr int EPW = 64 / LPE;
    int g = blockIdx.x;
    int z, nb;
    if (tbatch > 1) {
        int gz = g & 7;
        int ph = g >> 3;
        nb = ph % (NN / 4);
        z = (ph / (NN / 4)) * 8 + gz;
    } else {
        z = 0;
        nb = g;
    }
    const half8* in8 = (const half8*)(in + (long)z * sIn);
    int wv = threadIdx.x >> 6;
    int node = nb * 4 + wv;
    int lane = threadIdx.x & 63;
    int c8 = lane & (LPE - 1);
    int el = lane / LPE;
    float acc[8] = {0.f, 0.f, 0.f, 0.f, 0.f, 0.f, 0.f, 0.f};
    if (el == 0) {
        half8 sv = in8[(long)node * LPE + c8];
        float sw = selfw[node];
#pragma unroll
        for (int i = 0; i < 8; ++i) acc[i] = sw * (float)sv[i];
    }
    int r1 = rp[node + 1];
    int j = rp[node] + el;
    for (; j + 3 * EPW < r1; j += 4 * EPW) {
        int s0 = srcs[j], s1 = srcs[j + EPW], s2 = srcs[j + 2 * EPW], s3 = srcs[j + 3 * EPW];
        float w0 = w[j], w1 = w[j + EPW], w2 = w[j + 2 * EPW], w3 = w[j + 3 * EPW];
        half8 v0 = in8[(long)s0 * LPE + c8];
        half8 v1 = in8[(long)s1 * LPE + c8];
        half8 v2 = in8[(long)s2 * LPE + c8];
        half8 v3 = in8[(long)s3 * LPE + c8];
#pragma unroll
        for (int i = 0; i < 8; ++i)
            acc[i] += w0 * (float)v0[i] + w1 * (float)v1[i] + w2 * (float)v2[i] + w3 * (float)v3[i];
    }
    for (; j < r1; j += EPW) {
        float wA = w[j];
        half8 vA = in8[(long)srcs[j] * LPE + c8];
#pragma unroll
        for (int i = 0; i < 8; ++i) acc[i] += wA * (float)vA[i];
    }
#pragma unroll
    for (int m = LPE; m < 64; m <<= 1) {
#pragma unroll
        for (int i = 0; i < 8; ++i) acc[i] += __shfl_xor(acc[i], m);
    }
    if (el == 0) {
        if (BIAS) {
            float4 b0 = *(const float4*)&bias[c8 * 8];
            float4 b1 = *(const float4*)&bias[c8 * 8 + 4];
            acc[0] += b0.x; acc[1] += b0.y; acc[2] += b0.z; acc[3] += b0.w;
            acc[4] += b1.x; acc[5] += b1.y; acc[6] += b1.z; acc[7] += b1.w;
        }
        if (RELU) {
#pragma unroll
            for (int i = 0; i < 8; ++i) acc[i] = fmaxf(acc[i], 0.f);
        }
        if (OUT32) {
            float* o = (float*)outv + (long)z * sOut + (long)node * (LPE * 8) + c8 * 8;
            *(float4*)o = make_float4(acc[0], acc[1], acc[2], acc[3]);
            *(float4*)(o + 4) = make_float4(acc[4], acc[5], acc[6], acc[7]);
        } else {
            half8 ov = {(h16)acc[0], (h16)acc[1], (h16)acc[2], (h16)acc[3],
                        (h16)acc[4], (h16)acc[5], (h16)acc[6], (h16)acc[7]};
            ((half8*)((h16*)outv + (long)z * sOut))[(long)node * LPE + c8] = ov;
        }
    }
}

// ---------------- fp16 MFMA GEMM: C[M,Nc] = act(A[M,K] @ B + bias) ----------------
// 128x64 tile per block, BK=32, 4 waves; wave w owns rows [w*32, w*32+32).
template <bool BIAS, bool RELU>
__global__ __launch_bounds__(256) void gemm_h(
    const h16* __restrict__ A, const h16* __restrict__ BT,
    const float* __restrict__ bias, h16* __restrict__ C,
    int M, int Nc, int K, long sA, long sC) {
    A += (long)blockIdx.z * sA;
    C += (long)blockIdx.z * sC;
    __shared__ h16 smem[9216];   // 18432 B: staging 7680 halfs; epilogue 128*72
    h16* As = smem;              // [128][40]
    h16* Bs = smem + 5120;       // [64][40]
    int tid = threadIdx.x;
    int bm = blockIdx.y * 128, bn = blockIdx.x * 64;
    int w = tid >> 6, lane = tid & 63;
    int l15 = lane & 15, quad = lane >> 4;
    int ar = tid >> 2, ks = (tid & 3) * 8;
    floatx4 acc[2][4] = {};
    for (int k0 = 0; k0 < K; k0 += 32) {
        half8 a0 = {}, a1 = {};
        if (bm + ar < M) a0 = *(const half8*)&A[(long)(bm + ar) * K + k0 + ks];
        if (bm + ar + 64 < M) a1 = *(const half8*)&A[(long)(bm + ar + 64) * K + k0 + ks];
        *(half8*)&As[ar * 40 + ks] = a0;
        *(half8*)&As[(ar + 64) * 40 + ks] = a1;
        *(half8*)&Bs[ar * 40 + ks] = *(const half8*)&BT[(long)(bn + ar) * K + k0 + ks];
        __syncthreads();
        half8 af0 = *(const half8*)&As[(w * 32 + l15) * 40 + quad * 8];
        half8 af1 = *(const half8*)&As[(w * 32 + 16 + l15) * 40 + quad * 8];
#pragma unroll
        for (int nt = 0; nt < 4; ++nt) {
            half8 bf = *(const half8*)&Bs[(nt * 16 + l15) * 40 + quad * 8];
            acc[0][nt] = __builtin_amdgcn_mfma_f32_16x16x32_f16(af0, bf, acc[0][nt], 0, 0, 0);
            acc[1][nt] = __builtin_amdgcn_mfma_f32_16x16x32_f16(af1, bf, acc[1][nt], 0, 0, 0);
        }
        __syncthreads();
    }
    h16* Cs = smem;  // [128][72]
#pragma unroll
    for (int nt = 0; nt < 4; ++nt) {
        float b = BIAS ? bias[bn + nt * 16 + l15] : 0.0f;
#pragma unroll
        for (int mf = 0; mf < 2; ++mf) {
#pragma unroll
            for (int r = 0; r < 4; ++r) {
                float v = acc[mf][nt][r] + b;
                if (RELU) v = fmaxf(v, 0.0f);
                Cs[(w * 32 + mf * 16 + quad * 4 + r) * 72 + nt * 16 + l15] = (h16)v;
            }
        }
    }
    __syncthreads();
#pragma unroll
    for (int p = 0; p < 2; ++p) {
        int r = (tid >> 2) + p * 64, sg = (tid & 3) * 16;
        if (bm + r < M) {
            half8 v0 = *(const half8*)&Cs[r * 72 + sg];
            half8 v1 = *(const half8*)&Cs[r * 72 + sg + 8];
            *(half8*)&C[(long)(bm + r) * Nc + bn + sg] = v0;
            *(half8*)&C[(long)(bm + r) * Nc + bn + sg + 8] = v1;
        }
    }
}

// ---------------- mean pool over nodes (fp16 in, fp32 out) ----------------
__global__ void col_mean_h(const h16* __restrict__ in, float* __restrict__ pooled, long sIn) {
    const h16* p = in + (long)blockIdx.z * sIn;
    float* pt = pooled + (long)blockIdx.z * HH;
    int c = threadIdx.x;
    int n0 = blockIdx.x * 64;
    int n1 = min(n0 + 64, NN);
    float acc = 0.f;
    for (int n = n0; n < n1; ++n) acc += (float)p[(long)n * HH + c];
    atomicAdd(&pt[c], acc * (1.0f / (float)NN));
}

__global__ void enc_head(const float* __restrict__ pooled, const float* __restrict__ Wfce,
                         const float* __restrict__ bfce, float* __restrict__ z) {
    int t = blockIdx.x, j = threadIdx.x;
    __shared__ float p[HH];
    for (int i = j; i < HH; i += 64) p[i] = pooled[t * HH + i];
    __syncthreads();
    float acc = bfce[j];
    for (int h = 0; h < HH; ++h) acc += p[h] * Wfce[h * LL + j];
    z[t * LL + j] = acc;
}

// ---------------- fused 2-layer LSTM + head, persistent 16-block kernel ----------
__global__ __launch_bounds__(256) void fused_lstm(
    const float* __restrict__ zenc,
    const float* __restrict__ Wih0, const float* __restrict__ Whh0,
    const float* __restrict__ bih0, const float* __restrict__ bhh0,
    const float* __restrict__ Wih1, const float* __restrict__ Whh1,
    const float* __restrict__ bih1, const float* __restrict__ bhh1,
    const float* __restrict__ Whead, const float* __restrict__ bhead,
    float* __restrict__ H1, float* __restrict__ H2,   // [17][256], row0 zeroed
    unsigned* __restrict__ bar, float* __restrict__ zdec) {
    __shared__ h16 Ws[256][64];
    __shared__ float Gs[16][64];
    __shared__ float part[4][64];
    __shared__ float hbuf[256];
    __shared__ float cbuf[16];
    int tid = threadIdx.x;
    int kq = tid >> 6;
    int col = tid & 63;
    int g4 = col >> 4, ul = col & 15;
    int u0 = blockIdx.x * 16;
    int jg = g4 * 256 + u0 + ul;
    unsigned gen = 0;

#define GBAR()                                                        \
    do {                                                              \
        __threadfence();                                              \
        __syncthreads();                                              \
        if (tid == 0) {                                               \
            ++gen;                                                    \
            atomicAdd(bar, 1u);                                       \
            while (atomicAdd(bar, 0u) < 16u * gen)                    \
                __builtin_amdgcn_s_sleep(2);                          \
        }                                                             \
        __syncthreads();                                              \
        __threadfence();                                              \
    } while (0)

    if (tid < 16) cbuf[tid] = 0.f;
    for (int idx = tid; idx < 256 * 64; idx += 256) {
        int k = idx >> 6, c = idx & 63;
        Ws[k][c] = (h16)Whh0[k * 1024 + (c >> 4) * 256 + u0 + (c & 15)];
    }
    {
        float b = bih0[jg] + bhh0[jg];
        float a0 = b, a1 = b, a2 = b, a3 = b;
        for (int k = 0; k < 64; ++k) {
            float wvv = Wih0[k * 1024 + jg];
            a0 += zenc[kq * 64 + k] * wvv;
            a1 += zenc[(kq + 4) * 64 + k] * wvv;
            a2 += zenc[(kq + 8) * 64 + k] * wvv;
            a3 += zenc[(kq + 12) * 64 + k] * wvv;
        }
        Gs[kq][col] = a0; Gs[kq + 4][col] = a1;
        Gs[kq + 8][col] = a2; Gs[kq + 12][col] = a3;
    }
    __syncthreads();
    for (int t = 1; t <= 16; ++t) {
        hbuf[tid] = H1[(t - 1) * 256 + tid];
        __syncthreads();
        float acc = 0.f;
#pragma unroll
        for (int i = 0; i < 64; ++i) acc += hbuf[kq * 64 + i] * (float)Ws[kq * 64 + i][col];
        part[kq][col] = acc;
        __syncthreads();
        if (tid < 16) {
            int u = tid;
            float i_ = Gs[t - 1][u]      + part[0][u]      + part[1][u]      + part[2][u]      + part[3][u];
            float f_ = Gs[t - 1][16 + u] + part[0][16 + u] + part[1][16 + u] + part[2][16 + u] + part[3][16 + u];
            float g_ = Gs[t - 1][32 + u] + part[0][32 + u] + part[1][32 + u] + part[2][32 + u] + part[3][32 + u];
            float o_ = Gs[t - 1][48 + u] + part[0][48 + u] + part[1][48 + u] + part[2][48 + u] + part[3][48 + u];
            float cc = sigm(f_) * cbuf[u] + sigm(i_) * tanhf(g_);
            cbuf[u] = cc;
            H1[t * 256 + u0 + u] = sigm(o_) * tanhf(cc);
        }
        GBAR();
    }
    if (tid < 16) cbuf[tid] = 0.f;
    for (int idx = tid; idx < 256 * 64; idx += 256) {
        int k = idx >> 6, c = idx & 63;
        Ws[k][c] = (h16)Whh1[k * 1024 + (c >> 4) * 256 + u0 + (c & 15)];
    }
    {
        float b = bih1[jg] + bhh1[jg];
        float a0 = b, a1 = b, a2 = b, a3 = b;
        for (int k = 0; k < 256; ++k) {
            float wvv = Wih1[k * 1024 + jg];
            a0 += H1[(kq + 1) * 256 + k] * wvv;
            a1 += H1[(kq + 5) * 256 + k] * wvv;
            a2 += H1[(kq + 9) * 256 + k] * wvv;
            a3 += H1[(kq + 13) * 256 + k] * wvv;
        }
        Gs[kq][col] = a0; Gs[kq + 4][col] = a1;
        Gs[kq + 8][col] = a2; Gs[kq + 12][col] = a3;
    }
    __syncthreads();
    for (int t = 1; t <= 16; ++t) {
        hbuf[tid] = H2[(t - 1) * 256 + tid];
        __syncthreads();
        float acc = 0.f;
#pragma unroll
        for (int i = 0; i < 64; ++i) acc += hbuf[kq * 64 + i] * (float)Ws[kq * 64 + i][col];
        part[kq][col] = acc;
        __syncthreads();
        if (tid < 16) {
            int u = tid;
            float i_ = Gs[t - 1][u]      + part[0][u]      + part[1][u]      + part[2][u]      + part[3][u];
            float f_ = Gs[t - 1][16 + u] + part[0][16 + u] + part[1][16 + u] + part[2][16 + u] + part[3][16 + u];
            float g_ = Gs[t - 1][32 + u] + part[0][32 + u] + part[1][32 + u] + part[2][32 + u] + part[3][32 + u];
            float o_ = Gs[t - 1][48 + u] + part[0][48 + u] + part[1][48 + u] + part[2][48 + u] + part[3][48 + u];
            float cc = sigm(f_) * cbuf[u] + sigm(i_) * tanhf(g_);
            cbuf[u] = cc;
            H2[t * 256 + u0 + u] = sigm(o_) * tanhf(cc);
        }
        GBAR();
    }
    if (blockIdx.x == 0 && tid < 64) {
        const float* hf = H2 + 16 * 256;
        float a = bhead[tid];
        for (int k = 0; k < 256; ++k) a += hf[k] * Whead[k * 64 + tid];
        zdec[tid] = a;
    }
#undef GBAR
}

// Xd = relu(z @ Wfcd + bfcd), fp16 out
__global__ void dec_fc(const float* __restrict__ z, const float* __restrict__ Wfcd,
                       const float* __restrict__ bfcd, h16* __restrict__ Xd) {
    __shared__ float zs_[LL];
    if (threadIdx.x < LL) zs_[threadIdx.x] = z[threadIdx.x];
    __syncthreads();
    long m = ((long)blockIdx.x * 256 + threadIdx.x) * 4;
    if (m >= (long)NN * LL) return;
    float4 acc = *(const float4*)&bfcd[m];
#pragma unroll
    for (int k = 0; k < LL; ++k) {
        float4 w4 = *(const float4*)&Wfcd[(long)k * (NN * (long)LL) + m];
        float zk = zs_[k];
        acc.x += zk * w4.x; acc.y += zk * w4.y; acc.z += zk * w4.z; acc.w += zk * w4.w;
    }
    half4 o = {(h16)fmaxf(acc.x, 0.f), (h16)fmaxf(acc.y, 0.f),
               (h16)fmaxf(acc.z, 0.f), (h16)fmaxf(acc.w, 0.f)};
    *(half4*)&Xd[m] = o;
}

// ---------------- host ----------------

extern "C" void kernel_launch(void* const* d_in, const int* in_sizes, int n_in,
                              void* d_out, int out_size, void* d_ws, size_t ws_size,
                              hipStream_t stream) {
    const float* xs = (const float*)d_in[0];
    const float* edge_attr = (const float*)d_in[1];
    const float* We0 = (const float*)d_in[2];  const float* be0 = (const float*)d_in[3];
    const float* We1 = (const float*)d_in[4];  const float* be1 = (const float*)d_in[5];
    const float* Wfce = (const float*)d_in[6]; const float* bfce = (const float*)d_in[7];
    const float* Wih0 = (const float*)d_in[8]; const float* Whh0 = (const float*)d_in[9];
    const float* bih0 = (const float*)d_in[10]; const float* bhh0 = (const float*)d_in[11];
    const float* Wih1 = (const float*)d_in[12]; const float* Whh1 = (const float*)d_in[13];
    const float* bih1 = (const float*)d_in[14]; const float* bhh1 = (const float*)d_in[15];
    const float* Whead = (const float*)d_in[16]; const float* bhead = (const float*)d_in[17];
    const float* Wfcd = (const float*)d_in[18]; const float* bfcd = (const float*)d_in[19];
    const float* Wd0 = (const float*)d_in[20]; const float* bd0 = (const float*)d_in[21];
    const float* Wd1 = (const float*)d_in[22]; const float* bd1 = (const float*)d_in[23];
    const float* Wd2 = (const float*)d_in[24]; const float* bd2 = (const float*)d_in[25];
    const int* eidx = (const int*)d_in[26];
    const int* esrc = eidx;
    const int* edst = eidx + EE;
    float* out = (float*)d_out;
    float* W = (float*)d_ws;

    // ---- fp32 workspace (float offsets) ----
    const long O_DEG = 0;            // [10000]
    const long O_CNT = 10000;        // [10000] i32
    const long O_CUR = 20000;        // [10000] i32
    const long O_POOL = 30000;       // [16*256]
    const long O_H1 = 34096;         // [17*256]
    const long O_H2 = 38448;         // [17*256]
    const long O_BAR = 42800;        // [16]
    const long ZFLOATS = 42816;
    const long O_DISE = 42816, O_DISD = 52816, O_SNE = 62816, O_SND = 72816;
    const long O_RP = 82816;         // 10016 ints
    const long O_SRCS = 92832;       // 320000 ints
    const long O_WENC = 412832;
    const long O_WDEC = 732832;
    const long O_ZENC = 1052832;     // 16*64
    const long O_ZDEC = 1053856;     // 64
    const long O_F16 = 1053920;      // 16B-aligned

    h16* Hbase = (h16*)(W + O_F16);
    const long HO_XS = 0;                       // 20,480,000
    const long HO_WE0T = 20480000;
    const long HO_WE1T = HO_WE0T + 32768;
    const long HO_WD0T = HO_WE1T + 65536;
    const long HO_WD1T = HO_WD0T + 16384;
    const long HO_WD2T = HO_WD1T + 65536;
    const long HO_XD = HO_WD2T + 32768;
    const long HO_B0 = HO_XD + 640000;

    const long SB0 = (long)NN * FF;   // 1,280,000 halfs / timestep
    const long SB1 = (long)NN * HH;   // 2,560,000

    const long needBatched = O_F16 * 4 + (HO_B0 + 16L * (SB0 + 2 * SB1)) * 2;
    const bool batched = (long)ws_size >= needBatched;
    const long tb = batched ? 16 : 1;
    const long hoB1 = HO_B0 + tb * SB0;
    const long hoB2 = hoB1 + tb * SB1;

    float* deg = W + O_DEG;
    int* cnt = (int*)(W + O_CNT);
    int* cur = (int*)(W + O_CUR);
    float* pooled = W + O_POOL;
    float* H1 = W + O_H1; float* H2 = W + O_H2;
    unsigned* bar = (unsigned*)(W + O_BAR);
    float* dise = W + O_DISE; float* disd = W + O_DISD;
    float* sne = W + O_SNE;   float* snd = W + O_SND;
    int* rp = (int*)(W + O_RP);
    int* srcs = (int*)(W + O_SRCS);
    float* wenc = W + O_WENC; float* wdec = W + O_WDEC;
    float* zenc = W + O_ZENC; float* zdec = W + O_ZDEC;
    h16* xsh = Hbase + HO_XS;
    h16* We0T = Hbase + HO_WE0T; h16* We1T = Hbase + HO_WE1T;
    h16* Wd0T = Hbase + HO_WD0T; h16* Wd1T = Hbase + HO_WD1T; h16* Wd2T = Hbase + HO_WD2T;
    h16* XDh = Hbase + HO_XD;
    h16* B0h = Hbase + HO_B0; h16* B1h = Hbase + hoB1; h16* B2h = Hbase + hoB2;

    // ---- preprocessing ----
    hipMemsetAsync(d_ws, 0, ZFLOATS * 4, stream);
    pre_deg<<<(EE + 255) / 256, 256, 0, stream>>>(esrc, edst, edge_attr, deg, cnt);
    pre_dis<<<(NN + 255) / 256, 256, 0, stream>>>(deg, cnt, dise, disd, sne, snd);
    scan_rowptr<<<1, 1024, 0, stream>>>(cnt, rp);
    pre_build<<<(EE + 255) / 256, 256, 0, stream>>>(esrc, edst, edge_attr, rp, cur, dise, disd,
                                                    srcs, wenc, wdec);
    cvt_f2h<<<20000, 256, 0, stream>>>(xs, xsh, (long)TT * NN * FF / 4);
    wcvt<<<(FF * HH + 255) / 256, 256, 0, stream>>>(We0, We0T, FF, HH);
    wcvt<<<(HH * HH + 255) / 256, 256, 0, stream>>>(We1, We1T, HH, HH);
    wcvt<<<(LL * HH + 255) / 256, 256, 0, stream>>>(Wd0, Wd0T, LL, HH);
    wcvt<<<(HH * HH + 255) / 256, 256, 0, stream>>>(Wd1, Wd1T, HH, HH);
    wcvt<<<(HH * FF + 255) / 256, 256, 0, stream>>>(Wd2, Wd2T, HH, FF);

    // ---- encoder ----
    if (batched) {
        spmm2<16, false, false, false><<<dim3(2500 * 16), 256, 0, stream>>>(
            xsh, B0h, rp, srcs, wenc, sne, nullptr, SB0, SB0, 16);
        gemm_h<true, true><<<dim3(4, 79, 16), 256, 0, stream>>>(
            B0h, We0T, be0, B1h, NN, HH, FF, SB0, SB1);
        gemm_h<false, false><<<dim3(4, 79, 16), 256, 0, stream>>>(
            B1h, We1T, nullptr, B2h, NN, HH, HH, SB1, SB1);
        spmm2<32, true, true, false><<<dim3(2500 * 16), 256, 0, stream>>>(
            B2h, B1h, rp, srcs, wenc, sne, be1, SB1, SB1, 16);
        col_mean_h<<<dim3(157, 1, 16), 256, 0, stream>>>(B1h, pooled, SB1);
    } else {
        for (int t = 0; t < TT; ++t) {
            spmm2<16, false, false, false><<<dim3(2500), 256, 0, stream>>>(
                xsh + (long)t * SB0, B0h, rp, srcs, wenc, sne, nullptr, 0, 0, 1);
            gemm_h<true, true><<<dim3(4, 79, 1), 256, 0, stream>>>(
                B0h, We0T, be0, B1h, NN, HH, FF, 0, 0);
            gemm_h<false, false><<<dim3(4, 79, 1), 256, 0, stream>>>(
                B1h, We1T, nullptr, B2h, NN, HH, HH, 0, 0);
            spmm2<32, true, true, false><<<dim3(2500), 256, 0, stream>>>(
                B2h, B1h, rp, srcs, wenc, sne, be1, 0, 0, 1);
            col_mean_h<<<dim3(157, 1, 1), 256, 0, stream>>>(B1h, pooled + t * HH, 0);
        }
    }
    enc_head<<<16, 64, 0, stream>>>(pooled, Wfce, bfce, zenc);

    // ---- fused LSTM ----
    fused_lstm<<<16, 256, 0, stream>>>(zenc, Wih0, Whh0, bih0, bhh0,
                                       Wih1, Whh1, bih1, bhh1,
                                       Whead, bhead, H1, H2, bar, zdec);

    // ---- decoder ----
    dec_fc<<<625, 256, 0, stream>>>(zdec, Wfcd, bfcd, XDh);
    spmm2<8, false, false, false><<<dim3(2500), 256, 0, stream>>>(
        XDh, B0h, rp, srcs, wdec, snd, nullptr, 0, 0, 1);
    gemm_h<true, true><<<dim3(4, 79, 1), 256, 0, stream>>>(
        B0h, Wd0T, bd0, B1h, NN, HH, LL, 0, 0);
    gemm_h<false, false><<<dim3(4, 79, 1), 256, 0, stream>>>(
        B1h, Wd1T, nullptr, B2h, NN, HH, HH, 0, 0);
    spmm2<32, true, true, false><<<dim3(2500), 256, 0, stream>>>(
        B2h, B1h, rp, srcs, wdec, snd, bd1, 0, 0, 1);
    gemm_h<false, false><<<dim3(2, 79, 1), 256, 0, stream>>>(
        B1h, Wd2T, nullptr, B0h, NN, FF, HH, 0, 0);
    spmm2<16, true, false, true><<<dim3(2500), 256, 0, stream>>>(
        B0h, out, rp, srcs, wdec, snd, bd2, 0, 0, 1);
}

// Round 5
// 1009.228 us; speedup vs baseline: 2.8054x; 1.0839x over previous
//
#include <hip/hip_runtime.h>
#include <math.h>

#define TT 16
#define NN 10000
#define EE 320000
#define FF 128
#define HH 256
#define LL 64
#define HLL 256

typedef _Float16 h16;
typedef _Float16 half4 __attribute__((ext_vector_type(4)));
typedef _Float16 half8 __attribute__((ext_vector_type(8)));
typedef float floatx4 __attribute__((ext_vector_type(4)));

__device__ __forceinline__ float sigm(float x) { return 1.0f / (1.0f + expf(-x)); }

// agent-scope relaxed atomics: coherent across XCDs without L2 flushes
__device__ __forceinline__ float aldf(const float* p) {
    return __hip_atomic_load(p, __ATOMIC_RELAXED, __HIP_MEMORY_SCOPE_AGENT);
}
__device__ __forceinline__ int aldi(const int* p) {
    return __hip_atomic_load(p, __ATOMIC_RELAXED, __HIP_MEMORY_SCOPE_AGENT);
}
__device__ __forceinline__ void astf(float* p, float v) {
    __hip_atomic_store(p, v, __ATOMIC_RELAXED, __HIP_MEMORY_SCOPE_AGENT);
}

// ---------------- preprocessing ----------------

__global__ void pre_deg(const int* __restrict__ src, const int* __restrict__ dst,
                        const float* __restrict__ ea, float* __restrict__ deg_enc,
                        int* __restrict__ cnt) {
    int e = blockIdx.x * 256 + threadIdx.x;
    if (e >= EE) return;
    int d = dst[e];
    atomicAdd(&deg_enc[d], ea[e]);
    atomicAdd(&cnt[d], 1);
}

__global__ void pre_dis(const float* __restrict__ deg_enc, const int* __restrict__ cnt,
                        float* __restrict__ dis_enc, float* __restrict__ dis_dec,
                        float* __restrict__ sn_enc, float* __restrict__ sn_dec) {
    int n = blockIdx.x * 256 + threadIdx.x;
    if (n >= NN) return;
    float de = deg_enc[n] + 1.0f;
    float dd = (float)cnt[n] + 1.0f;
    dis_enc[n] = rsqrtf(de);
    dis_dec[n] = rsqrtf(dd);
    sn_enc[n] = 1.0f / de;
    sn_dec[n] = 1.0f / dd;
}

__global__ void scan_rowptr(const int* __restrict__ cnt, int* __restrict__ row_ptr) {
    __shared__ int sb[1024];
    int tx = threadIdx.x;
    int run = 0;
    if (tx == 0) row_ptr[0] = 0;
    for (int base = 0; base < NN; base += 1024) {
        int i = base + tx;
        int v = (i < NN) ? cnt[i] : 0;
        sb[tx] = v;
        __syncthreads();
        for (int off = 1; off < 1024; off <<= 1) {
            int t = (tx >= off) ? sb[tx - off] : 0;
            __syncthreads();
            sb[tx] += t;
            __syncthreads();
        }
        if (i < NN) row_ptr[i + 1] = run + sb[tx];
        run += sb[1023];
        __syncthreads();
    }
}

__global__ void pre_build(const int* __restrict__ src, const int* __restrict__ dst,
                          const float* __restrict__ ea, const int* __restrict__ row_ptr,
                          int* __restrict__ cursor, const float* __restrict__ dis_enc,
                          const float* __restrict__ dis_dec, int* __restrict__ src_s,
                          float* __restrict__ w_enc, float* __restrict__ w_dec) {
    int e = blockIdx.x * 256 + threadIdx.x;
    if (e >= EE) return;
    int s = src[e], d = dst[e];
    int pos = row_ptr[d] + atomicAdd(&cursor[d], 1);
    src_s[pos] = s;
    w_enc[pos] = dis_enc[s] * ea[e] * dis_enc[d];
    w_dec[pos] = dis_dec[s] * dis_dec[d];
}

// ---------------- fp32 -> fp16 conversions ----------------

__global__ void cvt_f2h(const float* __restrict__ src, h16* __restrict__ dst, long n4) {
    long i = (long)blockIdx.x * 256 + threadIdx.x;
    if (i >= n4) return;
    float4 v = ((const float4*)src)[i];
    half4 o = {(h16)v.x, (h16)v.y, (h16)v.z, (h16)v.w};
    ((half4*)dst)[i] = o;
}

// W [K][N] fp32 -> WT [N][K] fp16
__global__ void wcvt(const float* __restrict__ Wsrc, h16* __restrict__ WT, int K, int N) {
    int i = blockIdx.x * 256 + threadIdx.x;
    if (i >= K * N) return;
    int n = i / K, k = i % K;
    WT[i] = (h16)Wsrc[(long)k * N + n];
}

// ---------------- sparse A @ X, multi-edge-per-wave (CSR, fp16 feats, fp32 acc) ----
template <int LPE, bool BIAS, bool RELU, bool OUT32>
__global__ __launch_bounds__(256) void spmm2(
    const h16* __restrict__ in, void* __restrict__ outv,
    const int* __restrict__ rp, const int* __restrict__ srcs,
    const float* __restrict__ w, const float* __restrict__ selfw,
    const float* __restrict__ bias, long sIn, long sOut, int tbatch) {
    constexpr int EPW = 64 / LPE;
    int g = blockIdx.x;
    int z, nb;
    if (tbatch > 1) {
        int gz = g & 7;
        int ph = g >> 3;
        nb = ph % (NN / 4);
        z = (ph / (NN / 4)) * 8 + gz;
    } else {
        z = 0;
        nb = g;
    }
    const half8* in8 = (const half8*)(in + (long)z * sIn);
    int wv = threadIdx.x >> 6;
    int node = nb * 4 + wv;
    int lane = threadIdx.x & 63;
    int c8 = lane & (LPE - 1);
    int el = lane / LPE;
    float acc[8] = {0.f, 0.f, 0.f, 0.f, 0.f, 0.f, 0.f, 0.f};
    if (el == 0) {
        half8 sv = in8[(long)node * LPE + c8];
        float sw = selfw[node];
#pragma unroll
        for (int i = 0; i < 8; ++i) acc[i] = sw * (float)sv[i];
    }
    int r1 = rp[node + 1];
    int j = rp[node] + el;
    for (; j + 3 * EPW < r1; j += 4 * EPW) {
        int s0 = srcs[j], s1 = srcs[j + EPW], s2 = srcs[j + 2 * EPW], s3 = srcs[j + 3 * EPW];
        float w0 = w[j], w1 = w[j + EPW], w2 = w[j + 2 * EPW], w3 = w[j + 3 * EPW];
        half8 v0 = in8[(long)s0 * LPE + c8];
        half8 v1 = in8[(long)s1 * LPE + c8];
        half8 v2 = in8[(long)s2 * LPE + c8];
        half8 v3 = in8[(long)s3 * LPE + c8];
#pragma unroll
        for (int i = 0; i < 8; ++i)
            acc[i] += w0 * (float)v0[i] + w1 * (float)v1[i] + w2 * (float)v2[i] + w3 * (float)v3[i];
    }
    for (; j < r1; j += EPW) {
        float wA = w[j];
        half8 vA = in8[(long)srcs[j] * LPE + c8];
#pragma unroll
        for (int i = 0; i < 8; ++i) acc[i] += wA * (float)vA[i];
    }
#pragma unroll
    for (int m = LPE; m < 64; m <<= 1) {
#pragma unroll
        for (int i = 0; i < 8; ++i) acc[i] += __shfl_xor(acc[i], m);
    }
    if (el == 0) {
        if (BIAS) {
            float4 b0 = *(const float4*)&bias[c8 * 8];
            float4 b1 = *(const float4*)&bias[c8 * 8 + 4];
            acc[0] += b0.x; acc[1] += b0.y; acc[2] += b0.z; acc[3] += b0.w;
            acc[4] += b1.x; acc[5] += b1.y; acc[6] += b1.z; acc[7] += b1.w;
        }
        if (RELU) {
#pragma unroll
            for (int i = 0; i < 8; ++i) acc[i] = fmaxf(acc[i], 0.f);
        }
        if (OUT32) {
            float* o = (float*)outv + (long)z * sOut + (long)node * (LPE * 8) + c8 * 8;
            *(float4*)o = make_float4(acc[0], acc[1], acc[2], acc[3]);
            *(float4*)(o + 4) = make_float4(acc[4], acc[5], acc[6], acc[7]);
        } else {
            half8 ov = {(h16)acc[0], (h16)acc[1], (h16)acc[2], (h16)acc[3],
                        (h16)acc[4], (h16)acc[5], (h16)acc[6], (h16)acc[7]};
            ((half8*)((h16*)outv + (long)z * sOut))[(long)node * LPE + c8] = ov;
        }
    }
}

// ---------------- fp16 MFMA GEMM: C[M,Nc] = act(A[M,K] @ B + bias) ----------------
template <bool BIAS, bool RELU>
__global__ __launch_bounds__(256) void gemm_h(
    const h16* __restrict__ A, const h16* __restrict__ BT,
    const float* __restrict__ bias, h16* __restrict__ C,
    int M, int Nc, int K, long sA, long sC) {
    A += (long)blockIdx.z * sA;
    C += (long)blockIdx.z * sC;
    __shared__ h16 smem[9216];
    h16* As = smem;              // [128][40]
    h16* Bs = smem + 5120;       // [64][40]
    int tid = threadIdx.x;
    int bm = blockIdx.y * 128, bn = blockIdx.x * 64;
    int w = tid >> 6, lane = tid & 63;
    int l15 = lane & 15, quad = lane >> 4;
    int ar = tid >> 2, ks = (tid & 3) * 8;
    floatx4 acc[2][4] = {};
    for (int k0 = 0; k0 < K; k0 += 32) {
        half8 a0 = {}, a1 = {};
        if (bm + ar < M) a0 = *(const half8*)&A[(long)(bm + ar) * K + k0 + ks];
        if (bm + ar + 64 < M) a1 = *(const half8*)&A[(long)(bm + ar + 64) * K + k0 + ks];
        *(half8*)&As[ar * 40 + ks] = a0;
        *(half8*)&As[(ar + 64) * 40 + ks] = a1;
        *(half8*)&Bs[ar * 40 + ks] = *(const half8*)&BT[(long)(bn + ar) * K + k0 + ks];
        __syncthreads();
        half8 af0 = *(const half8*)&As[(w * 32 + l15) * 40 + quad * 8];
        half8 af1 = *(const half8*)&As[(w * 32 + 16 + l15) * 40 + quad * 8];
#pragma unroll
        for (int nt = 0; nt < 4; ++nt) {
            half8 bf = *(const half8*)&Bs[(nt * 16 + l15) * 40 + quad * 8];
            acc[0][nt] = __builtin_amdgcn_mfma_f32_16x16x32_f16(af0, bf, acc[0][nt], 0, 0, 0);
            acc[1][nt] = __builtin_amdgcn_mfma_f32_16x16x32_f16(af1, bf, acc[1][nt], 0, 0, 0);
        }
        __syncthreads();
    }
    h16* Cs = smem;  // [128][72]
#pragma unroll
    for (int nt = 0; nt < 4; ++nt) {
        float b = BIAS ? bias[bn + nt * 16 + l15] : 0.0f;
#pragma unroll
        for (int mf = 0; mf < 2; ++mf) {
#pragma unroll
            for (int r = 0; r < 4; ++r) {
                float v = acc[mf][nt][r] + b;
                if (RELU) v = fmaxf(v, 0.0f);
                Cs[(w * 32 + mf * 16 + quad * 4 + r) * 72 + nt * 16 + l15] = (h16)v;
            }
        }
    }
    __syncthreads();
#pragma unroll
    for (int p = 0; p < 2; ++p) {
        int r = (tid >> 2) + p * 64, sg = (tid & 3) * 16;
        if (bm + r < M) {
            half8 v0 = *(const half8*)&Cs[r * 72 + sg];
            half8 v1 = *(const half8*)&Cs[r * 72 + sg + 8];
            *(half8*)&C[(long)(bm + r) * Nc + bn + sg] = v0;
            *(half8*)&C[(long)(bm + r) * Nc + bn + sg + 8] = v1;
        }
    }
}

// ---------------- mean pool over nodes (fp16 in, fp32 out) ----------------
__global__ void col_mean_h(const h16* __restrict__ in, float* __restrict__ pooled, long sIn) {
    const h16* p = in + (long)blockIdx.z * sIn;
    float* pt = pooled + (long)blockIdx.z * HH;
    int c = threadIdx.x;
    int n0 = blockIdx.x * 64;
    int n1 = min(n0 + 64, NN);
    float acc = 0.f;
    for (int n = n0; n < n1; ++n) acc += (float)p[(long)n * HH + c];
    atomicAdd(&pt[c], acc * (1.0f / (float)NN));
}

__global__ void enc_head(const float* __restrict__ pooled, const float* __restrict__ Wfce,
                         const float* __restrict__ bfce, float* __restrict__ z) {
    int t = blockIdx.x, j = threadIdx.x;
    __shared__ float p[HH];
    for (int i = j; i < HH; i += 64) p[i] = pooled[t * HH + i];
    __syncthreads();
    float acc = bfce[j];
    for (int h = 0; h < HH; ++h) acc += p[h] * Wfce[h * LL + j];
    z[t * LL + j] = acc;
}

// ---------------- pipelined 2-layer LSTM + head: 32 blocks, fence-free -------
// Blocks 0-15: layer 1 (block b owns units b*16..b*16+16). Blocks 16-31: layer 2,
// running one step behind layer 1 (wavefront pipeline). All cross-block h
// exchange via agent-scope relaxed atomics (bypass non-coherent XCD L2s);
// per-step ready counters cnt1[t]/cnt2[t]; producer orders stores with
// s_waitcnt(0) before the counter bump. No __threadfence anywhere.
__global__ __launch_bounds__(256) void lstm_pipe(
    const float* __restrict__ zenc,
    const float* __restrict__ Wih0, const float* __restrict__ Whh0,
    const float* __restrict__ bih0, const float* __restrict__ bhh0,
    const float* __restrict__ Wih1, const float* __restrict__ Whh1,
    const float* __restrict__ bih1, const float* __restrict__ bhh1,
    const float* __restrict__ Whead, const float* __restrict__ bhead,
    float* __restrict__ H1, float* __restrict__ H2,   // [17][256]
    int* __restrict__ cnt1, int* __restrict__ cnt2, float* __restrict__ zdec) {
    __shared__ h16 Wr[256 * 64];   // recurrent weight slice
    __shared__ h16 Wx[256 * 64];   // layer2: Wih1 slice
    __shared__ float Gs[16 * 64];  // layer1: precomputed input gates
    __shared__ float part[4 * 64];
    __shared__ float hx[256];
    __shared__ float hp[256];
    __shared__ float cbuf[16];
    int tid = threadIdx.x, kq = tid >> 6, col = tid & 63;
    int g4 = col >> 4, ul = col & 15;
    bool lay2 = blockIdx.x >= 16;
    int ub = blockIdx.x & 15;
    int u0 = ub * 16;
    int jg = g4 * 256 + u0 + ul;
    if (tid < 16) cbuf[tid] = 0.f;

    if (!lay2) {
        for (int idx = tid; idx < 256 * 64; idx += 256) {
            int k = idx >> 6, c = idx & 63;
            Wr[idx] = (h16)Whh0[k * 1024 + (c >> 4) * 256 + u0 + (c & 15)];
        }
        {
            float b = bih0[jg] + bhh0[jg];
            float a0 = b, a1 = b, a2 = b, a3 = b;
            for (int k = 0; k < 64; ++k) {
                float wv = Wih0[k * 1024 + jg];
                a0 += zenc[kq * 64 + k] * wv;
                a1 += zenc[(kq + 4) * 64 + k] * wv;
                a2 += zenc[(kq + 8) * 64 + k] * wv;
                a3 += zenc[(kq + 12) * 64 + k] * wv;
            }
            Gs[kq * 64 + col] = a0; Gs[(kq + 4) * 64 + col] = a1;
            Gs[(kq + 8) * 64 + col] = a2; Gs[(kq + 12) * 64 + col] = a3;
        }
        __syncthreads();
        for (int t = 1; t <= 16; ++t) {
            if (tid == 0 && t > 1)
                while (aldi(&cnt1[t - 1]) < 16) __builtin_amdgcn_s_sleep(1);
            __syncthreads();
            hx[tid] = (t == 1) ? 0.f : aldf(&H1[(t - 1) * 256 + tid]);
            __syncthreads();
            float acc = 0.f;
#pragma unroll
            for (int i = 0; i < 64; ++i)
                acc += hx[kq * 64 + i] * (float)Wr[(kq * 64 + i) * 64 + col];
            part[kq * 64 + col] = acc;
            __syncthreads();
            if (tid < 16) {
                int u = tid;
                float i_ = Gs[(t - 1) * 64 + u]      + part[u]       + part[64 + u]       + part[128 + u]       + part[192 + u];
                float f_ = Gs[(t - 1) * 64 + 16 + u] + part[16 + u]  + part[80 + u]       + part[144 + u]       + part[208 + u];
                float g_ = Gs[(t - 1) * 64 + 32 + u] + part[32 + u]  + part[96 + u]       + part[160 + u]       + part[224 + u];
                float o_ = Gs[(t - 1) * 64 + 48 + u] + part[48 + u]  + part[112 + u]      + part[176 + u]       + part[240 + u];
                float cc = sigm(f_) * cbuf[u] + sigm(i_) * tanhf(g_);
                cbuf[u] = cc;
                astf(&H1[t * 256 + u0 + u], sigm(o_) * tanhf(cc));
                __builtin_amdgcn_s_waitcnt(0);
                if (tid == 0)
                    __hip_atomic_fetch_add(&cnt1[t], 1, __ATOMIC_RELAXED, __HIP_MEMORY_SCOPE_AGENT);
            }
        }
    } else {
        for (int idx = tid; idx < 256 * 64; idx += 256) {
            int k = idx >> 6, c = idx & 63;
            int gcol = (c >> 4) * 256 + u0 + (c & 15);
            Wr[idx] = (h16)Whh1[k * 1024 + gcol];
            Wx[idx] = (h16)Wih1[k * 1024 + gcol];
        }
        float bj = bih1[jg] + bhh1[jg];
        __syncthreads();
        for (int t = 1; t <= 16; ++t) {
            if (tid == 0) {
                while (aldi(&cnt1[t]) < 16) __builtin_amdgcn_s_sleep(1);
                if (t > 1)
                    while (aldi(&cnt2[t - 1]) < 16) __builtin_amdgcn_s_sleep(1);
            }
            __syncthreads();
            hx[tid] = aldf(&H1[t * 256 + tid]);
            hp[tid] = (t == 1) ? 0.f : aldf(&H2[(t - 1) * 256 + tid]);
            __syncthreads();
            float acc = (kq == 0) ? bj : 0.f;
#pragma unroll
            for (int i = 0; i < 64; ++i) {
                int k = kq * 64 + i;
                acc += hx[k] * (float)Wx[k * 64 + col] + hp[k] * (float)Wr[k * 64 + col];
            }
            part[kq * 64 + col] = acc;
            __syncthreads();
            if (tid < 16) {
                int u = tid;
                float i_ = part[u]      + part[64 + u]  + part[128 + u] + part[192 + u];
                float f_ = part[16 + u] + part[80 + u]  + part[144 + u] + part[208 + u];
                float g_ = part[32 + u] + part[96 + u]  + part[160 + u] + part[224 + u];
                float o_ = part[48 + u] + part[112 + u] + part[176 + u] + part[240 + u];
                float cc = sigm(f_) * cbuf[u] + sigm(i_) * tanhf(g_);
                cbuf[u] = cc;
                astf(&H2[t * 256 + u0 + u], sigm(o_) * tanhf(cc));
                __builtin_amdgcn_s_waitcnt(0);
                if (tid == 0)
                    __hip_atomic_fetch_add(&cnt2[t], 1, __ATOMIC_RELAXED, __HIP_MEMORY_SCOPE_AGENT);
            }
        }
        if (ub == 0) {
            if (tid == 0)
                while (aldi(&cnt2[16]) < 16) __builtin_amdgcn_s_sleep(1);
            __syncthreads();
            hp[tid] = aldf(&H2[16 * 256 + tid]);
            __syncthreads();
            if (tid < 64) {
                float a = bhead[tid];
                for (int k = 0; k < 256; ++k) a += hp[k] * Whead[k * 64 + tid];
                zdec[tid] = a;
            }
        }
    }
}

// Xd = relu(z @ Wfcd + bfcd), fp16 out
__global__ void dec_fc(const float* __restrict__ z, const float* __restrict__ Wfcd,
                       const float* __restrict__ bfcd, h16* __restrict__ Xd) {
    __shared__ float zs_[LL];
    if (threadIdx.x < LL) zs_[threadIdx.x] = z[threadIdx.x];
    __syncthreads();
    long m = ((long)blockIdx.x * 256 + threadIdx.x) * 4;
    if (m >= (long)NN * LL) return;
    float4 acc = *(const float4*)&bfcd[m];
#pragma unroll
    for (int k = 0; k < LL; ++k) {
        float4 w4 = *(const float4*)&Wfcd[(long)k * (NN * (long)LL) + m];
        float zk = zs_[k];
        acc.x += zk * w4.x; acc.y += zk * w4.y; acc.z += zk * w4.z; acc.w += zk * w4.w;
    }
    half4 o = {(h16)fmaxf(acc.x, 0.f), (h16)fmaxf(acc.y, 0.f),
               (h16)fmaxf(acc.z, 0.f), (h16)fmaxf(acc.w, 0.f)};
    *(half4*)&Xd[m] = o;
}

// ---------------- host ----------------

extern "C" void kernel_launch(void* const* d_in, const int* in_sizes, int n_in,
                              void* d_out, int out_size, void* d_ws, size_t ws_size,
                              hipStream_t stream) {
    const float* xs = (const float*)d_in[0];
    const float* edge_attr = (const float*)d_in[1];
    const float* We0 = (const float*)d_in[2];  const float* be0 = (const float*)d_in[3];
    const float* We1 = (const float*)d_in[4];  const float* be1 = (const float*)d_in[5];
    const float* Wfce = (const float*)d_in[6]; const float* bfce = (const float*)d_in[7];
    const float* Wih0 = (const float*)d_in[8]; const float* Whh0 = (const float*)d_in[9];
    const float* bih0 = (const float*)d_in[10]; const float* bhh0 = (const float*)d_in[11];
    const float* Wih1 = (const float*)d_in[12]; const float* Whh1 = (const float*)d_in[13];
    const float* bih1 = (const float*)d_in[14]; const float* bhh1 = (const float*)d_in[15];
    const float* Whead = (const float*)d_in[16]; const float* bhead = (const float*)d_in[17];
    const float* Wfcd = (const float*)d_in[18]; const float* bfcd = (const float*)d_in[19];
    const float* Wd0 = (const float*)d_in[20]; const float* bd0 = (const float*)d_in[21];
    const float* Wd1 = (const float*)d_in[22]; const float* bd1 = (const float*)d_in[23];
    const float* Wd2 = (const float*)d_in[24]; const float* bd2 = (const float*)d_in[25];
    const int* eidx = (const int*)d_in[26];
    const int* esrc = eidx;
    const int* edst = eidx + EE;
    float* out = (float*)d_out;
    float* W = (float*)d_ws;

    // ---- fp32 workspace (float offsets) ----
    // zeroed region:
    const long O_DEG = 0;            // [10000]
    const long O_CNT = 10000;        // [10000] i32
    const long O_CUR = 20000;        // [10000] i32
    const long O_POOL = 30000;       // [16*256]
    const long O_H1 = 34096;         // [17*256]
    const long O_H2 = 38448;         // [17*256]
    const long O_CNT1 = 42800;       // [32] i32
    const long O_CNT2 = 42832;       // [32] i32
    const long ZFLOATS = 42864;
    // non-zeroed:
    const long O_DISE = 42864, O_DISD = 52864, O_SNE = 62864, O_SND = 72864;
    const long O_RP = 82864;         // 10016 ints
    const long O_SRCS = 92880;       // 320000 ints
    const long O_WENC = 412880;
    const long O_WDEC = 732880;
    const long O_ZENC = 1052880;     // 16*64
    const long O_ZDEC = 1053904;     // 64
    const long O_F16 = 1053968;      // 16B-aligned (1053968*4 % 16 == 0)

    h16* Hbase = (h16*)(W + O_F16);
    const long HO_XS = 0;                       // 20,480,000
    const long HO_WE0T = 20480000;
    const long HO_WE1T = HO_WE0T + 32768;
    const long HO_WD0T = HO_WE1T + 65536;
    const long HO_WD1T = HO_WD0T + 16384;
    const long HO_WD2T = HO_WD1T + 65536;
    const long HO_XD = HO_WD2T + 32768;
    const long HO_B0 = HO_XD + 640000;

    const long SB0 = (long)NN * FF;   // 1,280,000 halfs / timestep
    const long SB1 = (long)NN * HH;   // 2,560,000

    const long needBatched = O_F16 * 4 + (HO_B0 + 16L * (SB0 + 2 * SB1)) * 2;
    const bool batched = (long)ws_size >= needBatched;
    const long tb = batched ? 16 : 1;
    const long hoB1 = HO_B0 + tb * SB0;
    const long hoB2 = hoB1 + tb * SB1;

    float* deg = W + O_DEG;
    int* cnt = (int*)(W + O_CNT);
    int* cur = (int*)(W + O_CUR);
    float* pooled = W + O_POOL;
    float* H1 = W + O_H1; float* H2 = W + O_H2;
    int* cnt1 = (int*)(W + O_CNT1); int* cnt2 = (int*)(W + O_CNT2);
    float* dise = W + O_DISE; float* disd = W + O_DISD;
    float* sne = W + O_SNE;   float* snd = W + O_SND;
    int* rp = (int*)(W + O_RP);
    int* srcs = (int*)(W + O_SRCS);
    float* wenc = W + O_WENC; float* wdec = W + O_WDEC;
    float* zenc = W + O_ZENC; float* zdec = W + O_ZDEC;
    h16* xsh = Hbase + HO_XS;
    h16* We0T = Hbase + HO_WE0T; h16* We1T = Hbase + HO_WE1T;
    h16* Wd0T = Hbase + HO_WD0T; h16* Wd1T = Hbase + HO_WD1T; h16* Wd2T = Hbase + HO_WD2T;
    h16* XDh = Hbase + HO_XD;
    h16* B0h = Hbase + HO_B0; h16* B1h = Hbase + hoB1; h16* B2h = Hbase + hoB2;

    // ---- preprocessing ----
    hipMemsetAsync(d_ws, 0, ZFLOATS * 4, stream);
    pre_deg<<<(EE + 255) / 256, 256, 0, stream>>>(esrc, edst, edge_attr, deg, cnt);
    pre_dis<<<(NN + 255) / 256, 256, 0, stream>>>(deg, cnt, dise, disd, sne, snd);
    scan_rowptr<<<1, 1024, 0, stream>>>(cnt, rp);
    pre_build<<<(EE + 255) / 256, 256, 0, stream>>>(esrc, edst, edge_attr, rp, cur, dise, disd,
                                                    srcs, wenc, wdec);
    cvt_f2h<<<20000, 256, 0, stream>>>(xs, xsh, (long)TT * NN * FF / 4);
    wcvt<<<(FF * HH + 255) / 256, 256, 0, stream>>>(We0, We0T, FF, HH);
    wcvt<<<(HH * HH + 255) / 256, 256, 0, stream>>>(We1, We1T, HH, HH);
    wcvt<<<(LL * HH + 255) / 256, 256, 0, stream>>>(Wd0, Wd0T, LL, HH);
    wcvt<<<(HH * HH + 255) / 256, 256, 0, stream>>>(Wd1, Wd1T, HH, HH);
    wcvt<<<(HH * FF + 255) / 256, 256, 0, stream>>>(Wd2, Wd2T, HH, FF);

    // ---- encoder ----
    if (batched) {
        spmm2<16, false, false, false><<<dim3(2500 * 16), 256, 0, stream>>>(
            xsh, B0h, rp, srcs, wenc, sne, nullptr, SB0, SB0, 16);
        gemm_h<true, true><<<dim3(4, 79, 16), 256, 0, stream>>>(
            B0h, We0T, be0, B1h, NN, HH, FF, SB0, SB1);
        gemm_h<false, false><<<dim3(4, 79, 16), 256, 0, stream>>>(
            B1h, We1T, nullptr, B2h, NN, HH, HH, SB1, SB1);
        spmm2<32, true, true, false><<<dim3(2500 * 16), 256, 0, stream>>>(
            B2h, B1h, rp, srcs, wenc, sne, be1, SB1, SB1, 16);
        col_mean_h<<<dim3(157, 1, 16), 256, 0, stream>>>(B1h, pooled, SB1);
    } else {
        for (int t = 0; t < TT; ++t) {
            spmm2<16, false, false, false><<<dim3(2500), 256, 0, stream>>>(
                xsh + (long)t * SB0, B0h, rp, srcs, wenc, sne, nullptr, 0, 0, 1);
            gemm_h<true, true><<<dim3(4, 79, 1), 256, 0, stream>>>(
                B0h, We0T, be0, B1h, NN, HH, FF, 0, 0);
            gemm_h<false, false><<<dim3(4, 79, 1), 256, 0, stream>>>(
                B1h, We1T, nullptr, B2h, NN, HH, HH, 0, 0);
            spmm2<32, true, true, false><<<dim3(2500), 256, 0, stream>>>(
                B2h, B1h, rp, srcs, wenc, sne, be1, 0, 0, 1);
            col_mean_h<<<dim3(157, 1, 1), 256, 0, stream>>>(B1h, pooled + t * HH, 0);
        }
    }
    enc_head<<<16, 64, 0, stream>>>(pooled, Wfce, bfce, zenc);

    // ---- pipelined LSTM (layer1 + layer2 concurrent, fence-free) ----
    lstm_pipe<<<32, 256, 0, stream>>>(zenc, Wih0, Whh0, bih0, bhh0,
                                      Wih1, Whh1, bih1, bhh1,
                                      Whead, bhead, H1, H2, cnt1, cnt2, zdec);

    // ---- decoder ----
    dec_fc<<<625, 256, 0, stream>>>(zdec, Wfcd, bfcd, XDh);
    spmm2<8, false, false, false><<<dim3(2500), 256, 0, stream>>>(
        XDh, B0h, rp, srcs, wdec, snd, nullptr, 0, 0, 1);
    gemm_h<true, true><<<dim3(4, 79, 1), 256, 0, stream>>>(
        B0h, Wd0T, bd0, B1h, NN, HH, LL, 0, 0);
    gemm_h<false, false><<<dim3(4, 79, 1), 256, 0, stream>>>(
        B1h, Wd1T, nullptr, B2h, NN, HH, HH, 0, 0);
    spmm2<32, true, true, false><<<dim3(2500), 256, 0, stream>>>(
        B2h, B1h, rp, srcs, wdec, snd, bd1, 0, 0, 1);
    gemm_h<false, false><<<dim3(2, 79, 1), 256, 0, stream>>>(
        B1h, Wd2T, nullptr, B0h, NN, FF, HH, 0, 0);
    spmm2<16, true, false, true><<<dim3(2500), 256, 0, stream>>>(
        B0h, out, rp, srcs, wdec, snd, bd2, 0, 0, 1);
}